// Round 16
// baseline (179.595 us; speedup 1.0000x reference)
//
#include <hip/hip_runtime.h>

typedef __attribute__((ext_vector_type(4))) float f32x4;
typedef __attribute__((ext_vector_type(8))) short bf16x8;

#define BN_EPS 1e-5f
constexpr int BATCH = 32;

static inline int cdiv(int a, int b) { return (a + b - 1) / b; }

__device__ __forceinline__ float lrelu(float v) { return v > 0.f ? v : 0.1f * v; }

__device__ __forceinline__ unsigned short f2bf(float f) {
    unsigned u = __float_as_uint(f);
    u = (u + 0x7FFFu + ((u >> 16) & 1u)) >> 16;
    return (unsigned short)u;
}
__device__ __forceinline__ float bf2f(unsigned short s) {
    return __uint_as_float(((unsigned)s) << 16);
}

// LDS XOR swizzles (elem units, preserve 16B store granules)
#define SWZ(e)  ((e) ^ ((((e) >> 6) & 3) << 3))

// async global->LDS, 16B per lane, wave-uniform LDS base (HW adds lane*16)
__device__ __forceinline__ void gload16(const unsigned short* g, unsigned short* l)
{
    __builtin_amdgcn_global_load_lds(
        (const __attribute__((address_space(1))) void*)g,
        (__attribute__((address_space(3))) void*)l,
        16, 0, 0);
}

__device__ __forceinline__ f32x4 shfl4(f32x4 v, int src)
{
    f32x4 r;
    r.x = __shfl(v.x, src, 32);
    r.y = __shfl(v.y, src, 32);
    r.z = __shfl(v.z, src, 32);
    r.w = __shfl(v.w, src, 32);
    return r;
}

// ---------------------------------------------------------------------------
// Per-block finalize of BN partials -> LDS stats (mean, rsqrt). Deterministic.
// ---------------------------------------------------------------------------
template<int C, int NS>
__device__ __forceinline__ void finalize_stats(const float2* __restrict__ part, int f,
                                               float inv, float* sstats)
{
    __shared__ float2 red[256];
    int t = threadIdx.x;
    int c = t % C, k = t / C;
    float s1 = 0.f, s2 = 0.f;
    for (int q = k; q < NS; q += 256 / C) {
        float2 p = part[(size_t)(f * C + c) * NS + q];
        s1 += p.x; s2 += p.y;
    }
    red[t] = make_float2(s1, s2);
    __syncthreads();
    for (int off = 128; off >= C; off >>= 1) {
        if (t < off) { red[t].x += red[t + off].x; red[t].y += red[t + off].y; }
        __syncthreads();
    }
    if (t < C) {
        float m = red[t].x * inv;
        float var = red[t].y * inv - m * m;
        sstats[2 * t]     = m;
        sstats[2 * t + 1] = rsqrtf(var + BN_EPS);
    }
    __syncthreads();
}

// ---------------------------------------------------------------------------
// Merged: encoder conv1 (blocks 0..511) + weight prep (blocks 512..2039).
// Weights written as pre-swizzled images: image[y] = orig[SWZ(y)].
// ---------------------------------------------------------------------------
__global__ __launch_bounds__(256) void conv1_prep(
    const float* __restrict__ fA, const float* __restrict__ fB,
    const float* __restrict__ w, const float* __restrict__ bias,
    unsigned short* __restrict__ outN, float2* __restrict__ part1,
    const float* wd1, const float* wd2, const float* wd3, const float* wd4,
    const float* wE2s, const float* wE3s,
    unsigned short* d1, unsigned short* d2, unsigned short* d3,
    unsigned short* d4, unsigned short* dE2, unsigned short* dE3,
    unsigned short* zb)
{
    const int gid = blockIdx.x;
    if (gid >= 512) {
        if (gid == 512 && threadIdx.x == 0) {
            int4 z = {0, 0, 0, 0};
            *(int4*)zb = z;
        }
        int idx = (gid - 512) * 256 + threadIdx.x;
        if (idx < 368640) {
            const float* src; unsigned short* dst; int MB, NOCB, CINS, COUT;
            if (idx < 221184)      { src = wd1; dst = d1; MB = 64; NOCB = 2; CINS = 169; COUT = 128; }
            else if (idx < 294912) { src = wd2; dst = d2; MB = 64; NOCB = 1; CINS = 128; COUT = 64; idx -= 221184; }
            else if (idx < 350208) { src = wd3; dst = d3; MB = 64; NOCB = 1; CINS = 96;  COUT = 64; idx -= 294912; }
            else                   { src = wd4; dst = d4; MB = 32; NOCB = 1; CINS = 64;  COUT = 32; idx -= 350208; }
            int lid = idx;
            int IMG = 9 * MB * 32;
            int chunk = lid / (NOCB * IMG);
            int r = lid % (NOCB * IMG);
            int ocb = r / IMG;
            int y = r % IMG;
            int z = SWZ(y);
            int row = z >> 5;
            int tap = (MB == 64) ? (row >> 6) : (row >> 5);
            int oc  = ocb * MB + (row & (MB - 1));
            int ic  = chunk * 32 + (z & 31);
            float v = (ic < CINS) ? src[((size_t)oc * CINS + ic) * 9 + tap] : 0.f;
            dst[lid] = f2bf(v);
        } else if (idx < 381952) {
            int lid = idx - 368640;
            int z = SWZ(lid);
            int row = z >> 5;
            int slot = row >> 5, ocr = row & 31;
            int c = z & 31;
            int tap = 2 * slot + (c >= 16 ? 1 : 0);
            int ic = c & 15;
            float v = (tap < 25) ? wE2s[((size_t)ocr * 16 + ic) * 25 + tap] : 0.f;
            dE2[lid] = f2bf(v);
        } else if (idx < 391168) {
            int lid = idx - 381952;
            int z = SWZ(lid);
            int row = z >> 5;
            int tap = row >> 5, ocr = row & 31;
            int ic = z & 31;
            dE3[lid] = f2bf(wE3s[((size_t)ocr * 32 + ic) * 9 + tap]);
        }
        return;
    }

    __shared__ float s_in[38][40];
    __shared__ float s_w[49][8];
    __shared__ float2 red1[4][8];

    const int tid = threadIdx.x;
    const int tx = tid & 15, ty = tid >> 4;
    const int tile = gid & 3;
    const int ocbase = ((gid >> 2) & 1) * 8;
    const int n = gid >> 3;
    const int x0 = (tile & 1) << 5;
    const int y0 = (tile >> 1) << 5;
    const float* in = (n < BATCH) ? (fA + (size_t)n * 4096) : (fB + (size_t)(n - BATCH) * 4096);

    for (int t = tid; t < 49 * 8; t += 256) {
        int oc = t & 7, k = t >> 3;
        s_w[k][oc] = w[(ocbase + oc) * 49 + k];
    }
    for (int t = tid; t < 38 * 38; t += 256) {
        int y = t / 38, x = t - (t / 38) * 38;
        int gy = y0 + y - 3, gx = x0 + x - 3;
        float v = 0.f;
        if ((unsigned)gy < 64u && (unsigned)gx < 64u) v = in[gy * 64 + gx];
        s_in[y][x] = v;
    }
    __syncthreads();

    float acc[8][4];
    #pragma unroll
    for (int oc = 0; oc < 8; ++oc) {
        float bv = bias[ocbase + oc];
        acc[oc][0] = bv; acc[oc][1] = bv; acc[oc][2] = bv; acc[oc][3] = bv;
    }
    #pragma unroll
    for (int kh = 0; kh < 7; ++kh) {
        #pragma unroll
        for (int kw = 0; kw < 7; ++kw) {
            float i00 = s_in[ty + kh][tx + kw];
            float i01 = s_in[ty + kh][tx + 16 + kw];
            float i10 = s_in[ty + 16 + kh][tx + kw];
            float i11 = s_in[ty + 16 + kh][tx + 16 + kw];
            #pragma unroll
            for (int oc = 0; oc < 8; ++oc) {
                float wv = s_w[kh * 7 + kw][oc];
                acc[oc][0] = fmaf(i00, wv, acc[oc][0]);
                acc[oc][1] = fmaf(i01, wv, acc[oc][1]);
                acc[oc][2] = fmaf(i10, wv, acc[oc][2]);
                acc[oc][3] = fmaf(i11, wv, acc[oc][3]);
            }
        }
    }
    #pragma unroll
    for (int i = 0; i < 2; ++i)
        #pragma unroll
        for (int j = 0; j < 2; ++j) {
            int k = i * 2 + j;
            int oy = y0 + ty + i * 16, ox = x0 + tx + j * 16;
            ushort4 p0, p1;
            p0.x = f2bf(acc[0][k]); p0.y = f2bf(acc[1][k]);
            p0.z = f2bf(acc[2][k]); p0.w = f2bf(acc[3][k]);
            p1.x = f2bf(acc[4][k]); p1.y = f2bf(acc[5][k]);
            p1.z = f2bf(acc[6][k]); p1.w = f2bf(acc[7][k]);
            unsigned short* dst = outN + ((size_t)n * 4096 + oy * 64 + ox) * 16 + ocbase;
            *(ushort4*)dst = p0;
            *(ushort4*)(dst + 4) = p1;
        }
    float v1[8], v2[8];
    #pragma unroll
    for (int oc = 0; oc < 8; ++oc) {
        v1[oc] = acc[oc][0] + acc[oc][1] + acc[oc][2] + acc[oc][3];
        v2[oc] = acc[oc][0] * acc[oc][0] + acc[oc][1] * acc[oc][1]
               + acc[oc][2] * acc[oc][2] + acc[oc][3] * acc[oc][3];
    }
    #pragma unroll
    for (int off = 32; off > 0; off >>= 1)
        #pragma unroll
        for (int oc = 0; oc < 8; ++oc) {
            v1[oc] += __shfl_down(v1[oc], off);
            v2[oc] += __shfl_down(v2[oc], off);
        }
    int wid = tid >> 6, lane = tid & 63;
    if (lane == 0)
        #pragma unroll
        for (int oc = 0; oc < 8; ++oc) red1[wid][oc] = make_float2(v1[oc], v2[oc]);
    __syncthreads();
    if (tid < 8) {
        float2 s = red1[0][tid];
        #pragma unroll
        for (int q = 1; q < 4; ++q) { s.x += red1[q][tid].x; s.y += red1[q][tid].y; }
        int f = n >> 5, slot = tile * 32 + (n & 31);      // NS=128
        part1[(size_t)(f * 16 + ocbase + tid) * 128 + slot] = s;
    }
}

// ---------------------------------------------------------------------------
// MFMA implicit-GEMM 3x3 pad-1 conv, NHWC bf16 in, fp32 accum.
// Weights: pre-swizzled images via global_load_lds. Inputs: async too when
// no BN-on-stage. OM: 0 bf16+lrelu; 1 f32; 2 lrelu + fused 1x1 (32->2) via
// shfl-reduce -> dout NCHW (MB=32); 3 f32 + BN partials.
// MODE 1 (f1): ch0-63 = upsample2x(d2) [async], 64-95 = skip w/ BN1 [VGPR].
// INBN: 0 none; 1 BN1 on skip channels; 2 BN on all input channels.
// ---------------------------------------------------------------------------
template<int CIN, int COUT, int H, int TH, int MODE, int OM, int INBN>
__global__ __launch_bounds__(256) void conv3x3_mfma(
    const unsigned short* __restrict__ in,
    const unsigned short* __restrict__ in2,
    const unsigned short* __restrict__ wT,
    const float* __restrict__ bias,
    unsigned short* __restrict__ out,
    float* __restrict__ dout,
    const float* __restrict__ w1x1,
    const float* __restrict__ b1x1,
    const float2* __restrict__ partIn,
    const float* __restrict__ gIn,
    const float* __restrict__ beIn,
    float2* __restrict__ partOut,
    const unsigned short* __restrict__ zb)
{
    constexpr int MB = (COUT >= 64) ? 64 : COUT;
    constexpr int MFRAGS = MB / 16;
    constexpr int WM = 2;
    constexpr int MW = MFRAGS / WM;
    constexpr int NW = 4 / MW;
    constexpr int WN = TH / NW;
    constexpr int NOCB = COUT / MB;
    constexpr int WIMG = 9 * MB * 32;
    constexpr int WTOT = WIMG / 512;
    constexpr int SIN_ELEMS = (TH + 2) * 18 * 32;
    constexpr int SIN_PAD = ((SIN_ELEMS + 511) / 512) * 512;
    constexpr int ITOT = SIN_PAD / 512;
    constexpr int NP = (TH + 2) * 18;     // valid granule-positions

    __shared__ unsigned short s_w[WIMG];
    __shared__ unsigned short s_in[SIN_PAD];
    __shared__ float sstIn[64];

    const int tid  = threadIdx.x;
    const int wid  = tid >> 6;
    const int lane = tid & 63;
    const int l15  = lane & 15;
    const int kg   = lane >> 4;
    constexpr int TILESX = H / 16;
    const int bx = blockIdx.x;
    const int x0 = (bx % TILESX) * 16;
    const int y0 = (bx / TILESX) * TH;
    const int ocbase = blockIdx.y * MB;
    const int n = blockIdx.z;

    const int mw = wid % MW;
    const int nw = wid / MW;

    if constexpr (INBN == 1)
        finalize_stats<32, 128>(partIn, 0, 1.f / (32.f * 4096.f), sstIn);
    if constexpr (INBN == 2)
        finalize_stats<32, 256>(partIn, n >> 5, 1.f / (32.f * 1024.f), sstIn);

    f32x4 acc[WM][WN];
    #pragma unroll
    for (int i = 0; i < WM; ++i) {
        #pragma unroll
        for (int r = 0; r < 4; ++r) {
            float bv = bias[ocbase + (mw * WM + i) * 16 + kg * 4 + r];
            #pragma unroll
            for (int j = 0; j < WN; ++j) acc[i][j][r] = bv;
        }
    }

    for (int c0 = 0; c0 < CIN; c0 += 32) {
        // async weight image copy (linear; values land pre-swizzled)
        {
            const unsigned short* wsrc = wT + ((size_t)((c0 >> 5) * NOCB + blockIdx.y)) * WIMG;
            for (int i = wid; i < WTOT; i += 4)
                gload16(wsrc + i * 512 + lane * 8, &s_w[i * 512]);
        }
        if constexpr (MODE == 0 && INBN == 0) {
            for (int i = wid; i < ITOT; i += 4) {
                int L = i * 512 + lane * 8;
                int z = SWZ(L);
                int p = z >> 5;
                int y = p / 18, x = p - y * 18;
                int gy = y0 - 1 + y, gx = x0 - 1 + x;
                const unsigned short* src = zb;
                if (p < NP && (unsigned)gy < (unsigned)H && (unsigned)gx < (unsigned)H)
                    src = &in[((size_t)(n * H + gy) * H + gx) * CIN + c0 + (z & 31)];
                gload16(src, &s_in[i * 512]);
            }
        } else if constexpr (MODE == 1) {
            if (c0 < 64) {
                for (int i = wid; i < ITOT; i += 4) {
                    int L = i * 512 + lane * 8;
                    int z = SWZ(L);
                    int p = z >> 5;
                    int y = p / 18, x = p - y * 18;
                    int gy = y0 - 1 + y, gx = x0 - 1 + x;
                    const unsigned short* src = zb;
                    if (p < NP && (unsigned)gy < 64u && (unsigned)gx < 64u)
                        src = &in[((size_t)(n * 32 + (gy >> 1)) * 32 + (gx >> 1)) * 64 + c0 + (z & 31)];
                    gload16(src, &s_in[i * 512]);
                }
            } else {
                for (int t = tid; t < NP * 4; t += 256) {
                    int sub = t & 3;
                    int p = t >> 2;
                    int y = p / 18, x = p - y * 18;
                    int gy = y0 - 1 + y, gx = x0 - 1 + x;
                    int4 v = {0, 0, 0, 0};
                    if ((unsigned)gy < 64u && (unsigned)gx < 64u) {
                        int f  = sub >> 1;
                        int cc = (sub & 1) * 8;
                        v = *(const int4*)&in2[((size_t)((f * BATCH + n) * 64 + gy) * 64 + gx) * 16 + cc];
                        unsigned short* e = (unsigned short*)&v;
                        #pragma unroll
                        for (int k = 0; k < 8; ++k) {
                            int gch = f * 16 + cc + k;
                            float xv = bf2f(e[k]);
                            e[k] = f2bf(lrelu((xv - sstIn[2 * gch]) * sstIn[2 * gch + 1]
                                              * gIn[cc + k] + beIn[cc + k]));
                        }
                    }
                    *(int4*)&s_in[SWZ(p * 32 + sub * 8)] = v;
                }
            }
        } else {
            for (int t = tid; t < NP * 4; t += 256) {
                int sub = t & 3;
                int p = t >> 2;
                int y = p / 18, x = p - y * 18;
                int gy = y0 - 1 + y, gx = x0 - 1 + x;
                int4 v = {0, 0, 0, 0};
                if ((unsigned)gy < (unsigned)H && (unsigned)gx < (unsigned)H) {
                    v = *(const int4*)&in[((size_t)(n * H + gy) * H + gx) * CIN + c0 + sub * 8];
                    if constexpr (INBN == 2) {
                        unsigned short* e = (unsigned short*)&v;
                        #pragma unroll
                        for (int k = 0; k < 8; ++k) {
                            int c = c0 + sub * 8 + k;
                            float xv = bf2f(e[k]);
                            e[k] = f2bf(lrelu((xv - sstIn[2 * c]) * sstIn[2 * c + 1] * gIn[c] + beIn[c]));
                        }
                    }
                }
                *(int4*)&s_in[SWZ(p * 32 + sub * 8)] = v;
            }
        }
        __syncthreads();   // drains vmcnt (incl. global_load_lds) + lgkm

        #pragma unroll
        for (int tap = 0; tap < 9; ++tap) {
            const int kh = tap / 3, kw = tap - (tap / 3) * 3;
            bf16x8 a[WM], b[WN];
            #pragma unroll
            for (int i = 0; i < WM; ++i) {
                int mf = mw * WM + i;
                a[i] = *(const bf16x8*)&s_w[SWZ((tap * MB + mf * 16 + l15) * 32 + kg * 8)];
            }
            #pragma unroll
            for (int j = 0; j < WN; ++j) {
                int nf = nw * WN + j;
                b[j] = *(const bf16x8*)&s_in[SWZ(((nf + kh) * 18 + l15 + kw) * 32 + kg * 8)];
            }
            #pragma unroll
            for (int i = 0; i < WM; ++i)
                #pragma unroll
                for (int j = 0; j < WN; ++j)
                    acc[i][j] = __builtin_amdgcn_mfma_f32_16x16x32_bf16(a[i], b[j], acc[i][j], 0, 0, 0);
        }
        __syncthreads();
    }

    if constexpr (OM == 2) {
        // fused 1x1 (32->2): per-lane partials over its 8 oc, shfl-reduce
        // across kg (lanes ^16, ^32). No LDS round-trip, dot on f32 accs.
        float w0l[8], w1l[8];
        #pragma unroll
        for (int i = 0; i < WM; ++i)
            #pragma unroll
            for (int r = 0; r < 4; ++r) {
                int oc = i * 16 + kg * 4 + r;
                w0l[i * 4 + r] = w1x1[oc];
                w1l[i * 4 + r] = w1x1[32 + oc];
            }
        #pragma unroll
        for (int j = 0; j < WN; ++j) {
            float s0 = 0.f, s1 = 0.f;
            #pragma unroll
            for (int i = 0; i < WM; ++i)
                #pragma unroll
                for (int r = 0; r < 4; ++r) {
                    float xv = lrelu(acc[i][j][r]);
                    s0 = fmaf(xv, w0l[i * 4 + r], s0);
                    s1 = fmaf(xv, w1l[i * 4 + r], s1);
                }
            s0 += __shfl_xor(s0, 16); s0 += __shfl_xor(s0, 32);
            s1 += __shfl_xor(s1, 16); s1 += __shfl_xor(s1, 32);
            if (kg == 0) {
                int gy = y0 + nw * WN + j, gx = x0 + l15;
                dout[((size_t)n * 2) * 4096 + gy * 64 + gx]     = s0 + b1x1[0];
                dout[((size_t)n * 2 + 1) * 4096 + gy * 64 + gx] = s1 + b1x1[1];
            }
        }
    } else {
        #pragma unroll
        for (int i = 0; i < WM; ++i) {
            int oc = ocbase + (mw * WM + i) * 16 + kg * 4;
            #pragma unroll
            for (int j = 0; j < WN; ++j) {
                int nf = nw * WN + j;
                int gy = y0 + nf, gx = x0 + l15;
                size_t base = ((size_t)(n * H + gy) * H + gx) * COUT + oc;
                if (OM == 0) {
                    ushort4 pk;
                    pk.x = f2bf(lrelu(acc[i][j][0]));
                    pk.y = f2bf(lrelu(acc[i][j][1]));
                    pk.z = f2bf(lrelu(acc[i][j][2]));
                    pk.w = f2bf(lrelu(acc[i][j][3]));
                    *(ushort4*)&out[base] = pk;
                } else {
                    *(f32x4*)&((float*)out)[base] = acc[i][j];
                }
            }
        }
    }

    if constexpr (OM == 3) {
        __shared__ float2 redC[4][4][8];
        float t1[2][4], t2[2][4];
        #pragma unroll
        for (int i = 0; i < 2; ++i)
            #pragma unroll
            for (int r = 0; r < 4; ++r) {
                float v0 = acc[i][0][r], v1 = acc[i][1][r];
                t1[i][r] = v0 + v1;
                t2[i][r] = v0 * v0 + v1 * v1;
            }
        #pragma unroll
        for (int off = 8; off > 0; off >>= 1)
            #pragma unroll
            for (int i = 0; i < 2; ++i)
                #pragma unroll
                for (int r = 0; r < 4; ++r) {
                    t1[i][r] += __shfl_down(t1[i][r], off);
                    t2[i][r] += __shfl_down(t2[i][r], off);
                }
        if (l15 == 0) {
            #pragma unroll
            for (int i = 0; i < 2; ++i)
                #pragma unroll
                for (int r = 0; r < 4; ++r)
                    redC[nw][kg][i * 4 + r] = make_float2(t1[i][r], t2[i][r]);
        }
        __syncthreads();
        if (tid < 32) {
            int oc = tid;
            int i = oc >> 4, kq = (oc & 15) >> 2, r = oc & 3;
            float2 s = redC[0][kq][i * 4 + r];
            #pragma unroll
            for (int q = 1; q < 4; ++q) {
                float2 p = redC[q][kq][i * 4 + r];
                s.x += p.x; s.y += p.y;
            }
            int f = n >> 5, slot = bx * 32 + (n & 31);   // NS=256
            partOut[(size_t)(f * 32 + oc) * 256 + slot] = s;
        }
    }
}

// ---------------------------------------------------------------------------
// Encoder conv2 (MFMA): 5x5 s2 pad2, 16->32. BN1 applied at staging.
// ---------------------------------------------------------------------------
__global__ __launch_bounds__(256) void conv2s_mfma(
    const unsigned short* __restrict__ in, const unsigned short* __restrict__ wS,
    const float* __restrict__ bias, unsigned short* __restrict__ outN,
    const float2* __restrict__ part1, const float* __restrict__ g1,
    const float* __restrict__ be1, float2* __restrict__ part2)
{
    __shared__ unsigned short s_w[13 * 32 * 32];
    __shared__ unsigned short s_in[20 * 36 * 16];
    __shared__ float2 redC[4][4][8];
    __shared__ float sst[32];

    const int tid = threadIdx.x;
    const int nw  = tid >> 6;
    const int lane = tid & 63;
    const int l15 = lane & 15;
    const int kg  = lane >> 4;
    const int x0 = (blockIdx.x & 1) * 16;
    const int y0 = (blockIdx.x >> 1) * 8;
    const int n  = blockIdx.z;

    for (int i = nw; i < 26; i += 4)
        gload16(wS + i * 512 + lane * 8, &s_w[i * 512]);

    finalize_stats<16, 128>(part1, n >> 5, 1.f / (32.f * 4096.f), sst);

    f32x4 acc[2][2];
    #pragma unroll
    for (int i = 0; i < 2; ++i) {
        #pragma unroll
        for (int r = 0; r < 4; ++r) {
            float bv = bias[i * 16 + kg * 4 + r];
            acc[i][0][r] = bv; acc[i][1][r] = bv;
        }
    }

    for (int t = tid; t < 1440; t += 256) {
        int sub = t & 1, p = t >> 1;
        int y = p / 36, x = p - y * 36;
        int gy = 2 * y0 - 2 + y, gx = 2 * x0 - 2 + x;
        int4 v = {0, 0, 0, 0};
        if ((unsigned)gy < 64u && (unsigned)gx < 64u) {
            v = *(const int4*)&in[((size_t)(n * 64 + gy) * 64 + gx) * 16 + sub * 8];
            unsigned short* e = (unsigned short*)&v;
            #pragma unroll
            for (int k = 0; k < 8; ++k) {
                int c = sub * 8 + k;
                float xv = bf2f(e[k]);
                e[k] = f2bf(lrelu((xv - sst[2 * c]) * sst[2 * c + 1] * g1[c] + be1[c]));
            }
        }
        *(int4*)&s_in[SWZ((y * 36 + x) * 16 + sub * 8)] = v;
    }
    __syncthreads();

    #pragma unroll
    for (int s = 0; s < 13; ++s) {
        int tA = 2 * s, tB = 2 * s + 1;
        int khA = tA / 5, kwA = tA % 5;
        int khB = tB / 5, kwB = tB % 5;
        int kh = (kg < 2) ? khA : khB;
        int kw = (kg < 2) ? kwA : kwB;
        int co = (kg & 1) * 8;
        bf16x8 a[2], b[2];
        a[0] = *(const bf16x8*)&s_w[SWZ((s * 32 + l15) * 32 + kg * 8)];
        a[1] = *(const bf16x8*)&s_w[SWZ((s * 32 + 16 + l15) * 32 + kg * 8)];
        #pragma unroll
        for (int j = 0; j < 2; ++j) {
            int py = nw * 2 + j;
            b[j] = *(const bf16x8*)&s_in[SWZ(((2 * py + kh) * 36 + 2 * l15 + kw) * 16 + co)];
        }
        acc[0][0] = __builtin_amdgcn_mfma_f32_16x16x32_bf16(a[0], b[0], acc[0][0], 0, 0, 0);
        acc[0][1] = __builtin_amdgcn_mfma_f32_16x16x32_bf16(a[0], b[1], acc[0][1], 0, 0, 0);
        acc[1][0] = __builtin_amdgcn_mfma_f32_16x16x32_bf16(a[1], b[0], acc[1][0], 0, 0, 0);
        acc[1][1] = __builtin_amdgcn_mfma_f32_16x16x32_bf16(a[1], b[1], acc[1][1], 0, 0, 0);
    }

    #pragma unroll
    for (int i = 0; i < 2; ++i)
        #pragma unroll
        for (int j = 0; j < 2; ++j) {
            int gy = y0 + nw * 2 + j, gx = x0 + l15;
            ushort4 pk;
            pk.x = f2bf(acc[i][j][0]); pk.y = f2bf(acc[i][j][1]);
            pk.z = f2bf(acc[i][j][2]); pk.w = f2bf(acc[i][j][3]);
            *(ushort4*)&outN[((size_t)(n * 32 + gy) * 32 + gx) * 32 + i * 16 + kg * 4] = pk;
        }

    float t1[2][4], t2[2][4];
    #pragma unroll
    for (int i = 0; i < 2; ++i)
        #pragma unroll
        for (int r = 0; r < 4; ++r) {
            float v0 = acc[i][0][r], v1 = acc[i][1][r];
            t1[i][r] = v0 + v1;
            t2[i][r] = v0 * v0 + v1 * v1;
        }
    #pragma unroll
    for (int off = 8; off > 0; off >>= 1)
        #pragma unroll
        for (int i = 0; i < 2; ++i)
            #pragma unroll
            for (int r = 0; r < 4; ++r) {
                t1[i][r] += __shfl_down(t1[i][r], off);
                t2[i][r] += __shfl_down(t2[i][r], off);
            }
    if (l15 == 0) {
        #pragma unroll
        for (int i = 0; i < 2; ++i)
            #pragma unroll
            for (int r = 0; r < 4; ++r)
                redC[nw][kg][i * 4 + r] = make_float2(t1[i][r], t2[i][r]);
    }
    __syncthreads();
    if (tid < 32) {
        int oc = tid;
        int i = oc >> 4, kq = (oc & 15) >> 2, r = oc & 3;
        float2 s = redC[0][kq][i * 4 + r];
        #pragma unroll
        for (int q = 1; q < 4; ++q) {
            float2 p = redC[q][kq][i * 4 + r];
            s.x += p.x; s.y += p.y;
        }
        int f = n >> 5, slot = blockIdx.x * 32 + (n & 31);
        part2[(size_t)(f * 32 + oc) * 256 + slot] = s;
    }
}

// ---------------------------------------------------------------------------
// BN3 finalize + lrelu + channel L2 norm. c3N f32 -> coarseN f32. Grid 256.
// ---------------------------------------------------------------------------
__global__ __launch_bounds__(256) void bn3_l2n_nhwc(const float* __restrict__ xN,
                             const float2* __restrict__ part3,
                             const float* __restrict__ g, const float* __restrict__ be,
                             float* __restrict__ outN)
{
    __shared__ float sst[64];
    int idx = blockIdx.x * blockDim.x + threadIdx.x;
    int f = idx >> 15;
    finalize_stats<32, 256>(part3, f, 1.f / (32.f * 1024.f), sst);
    const float* src = xN + (size_t)idx * 32;
    float v[32];
    float ss = 0.f;
    #pragma unroll
    for (int c = 0; c < 32; ++c) {
        float t = lrelu((src[c] - sst[2 * c]) * sst[2 * c + 1] * g[c] + be[c]);
        v[c] = t; ss += t * t;
    }
    float inv = 1.f / fmaxf(sqrtf(ss), 1e-12f);
    float* dst = outN + (size_t)idx * 32;
    #pragma unroll
    for (int c = 0; c < 32; ++c) dst[c] = v[c] * inv;
}

// ---------------------------------------------------------------------------
// Correlation, register+shfl version. grid (32 h, B, 2). Thread (w, gq)
// holds A[h][w] and B[gh][w] rows in regs; neighbor positions via
// __shfl(width=32) within the gq segment. Only sC (6 KB) in LDS.
// ---------------------------------------------------------------------------
__global__ __launch_bounds__(256) void corr_split(const float* __restrict__ xN,
                                                  unsigned short* __restrict__ cost)
{
    __shared__ unsigned short sC[32][96];

    const int h = blockIdx.x, b = blockIdx.y, half = blockIdx.z;
    const int ROWS = half ? 6 : 7;
    const int w  = threadIdx.x & 31;
    const int gq = threadIdx.x >> 5;     // 0..7 (segment-uniform)

    // A row h, position w -> regs (shared across gq via cache)
    f32x4 a[8];
    const float* Ap = xN + ((size_t)b * 1024 + h * 32 + w) * 32;
    #pragma unroll
    for (int gr = 0; gr < 8; ++gr) a[gr] = *(const f32x4*)&Ap[gr * 4];

    // B row gh = h + half*7 + gq - 6, position w -> regs (zero if OOB)
    int gh = h + half * 7 + gq - 6;
    f32x4 bv[8];
    #pragma unroll
    for (int gr = 0; gr < 8; ++gr) { bv[gr].x = 0.f; bv[gr].y = 0.f; bv[gr].z = 0.f; bv[gr].w = 0.f; }
    if (gq < ROWS && (unsigned)gh < 32u) {
        const float* Bp = xN + ((size_t)(BATCH + b) * 1024 + gh * 32 + w) * 32;
        #pragma unroll
        for (int gr = 0; gr < 8; ++gr) bv[gr] = *(const f32x4*)&Bp[gr * 4];
    }

    if (gq < ROWS) {                      // uniform within each 32-lane segment
        #pragma unroll
        for (int dx = 0; dx < 13; ++dx) {
            int wb = w + dx - 6;
            float s = 0.f;
            #pragma unroll
            for (int gr = 0; gr < 8; ++gr) {
                f32x4 t = shfl4(bv[gr], wb & 31);
                s += a[gr].x * t.x + a[gr].y * t.y + a[gr].z * t.z + a[gr].w * t.w;
            }
            if ((unsigned)wb >= 32u) s = 0.f;
            sC[w][gq * 13 + dx] = f2bf(s);
        }
    }
    __syncthreads();

    const int ND = ROWS * 13;            // 91 or 78
    for (int t = threadIdx.x; t < 32 * ND; t += 256) {
        int ww = t / ND;
        int d  = t - ww * ND;
        cost[((size_t)(b * 1024) + h * 32 + ww) * 192 + half * 91 + d] = sC[ww][d];
    }
}

// ---------------------------------------------------------------------------
extern "C" void kernel_launch(void* const* d_in, const int* in_sizes, int n_in,
                              void* d_out, int out_size, void* d_ws, size_t ws_size,
                              hipStream_t stream)
{
    const float* frameA = (const float*)d_in[0];
    const float* frameB = (const float*)d_in[1];
    const float* w1  = (const float*)d_in[2];
    const float* b1  = (const float*)d_in[3];
    const float* g1  = (const float*)d_in[4];
    const float* be1 = (const float*)d_in[5];
    const float* w2  = (const float*)d_in[6];
    const float* b2  = (const float*)d_in[7];
    const float* g2  = (const float*)d_in[8];
    const float* be2 = (const float*)d_in[9];
    const float* w3  = (const float*)d_in[10];
    const float* b3  = (const float*)d_in[11];
    const float* g3  = (const float*)d_in[12];
    const float* be3 = (const float*)d_in[13];
    const float* wc1 = (const float*)d_in[14];
    const float* bc1 = (const float*)d_in[15];
    const float* wc2 = (const float*)d_in[16];
    const float* bc2 = (const float*)d_in[17];
    const float* wf1 = (const float*)d_in[18];
    const float* bf1 = (const float*)d_in[19];
    const float* wf2 = (const float*)d_in[20];
    const float* bf2 = (const float*)d_in[21];
    const float* wo  = (const float*)d_in[22];
    const float* bo  = (const float*)d_in[23];

    // workspace layout
    float* ws      = (float*)d_ws;
    float* c3N     = ws;                              // [64][1024][32] f32  2,097,152
    float* coarseN = c3N + 2097152;                   // [64][1024][32] f32  2,097,152
    float2* part1  = (float2*)(coarseN + 2097152);    // 4096  float2 (BN1, NS=128)
    float2* part2  = part1 + 4096;                    // 16384 float2 (BN2, NS=256)
    float2* part3  = part2 + 16384;                   // 16384 float2 (BN3, NS=256)
    unsigned short* fineN = (unsigned short*)(part3 + 16384);  // [64][64][64][16] pre-BN
    unsigned short* h2bf  = fineN + 4194304;   // [64][32][32][32]  pre-BN2
    unsigned short* costN = h2bf + 2097152;    // [B][32][32][192]
    unsigned short* d1    = costN + 6291456;   // [B][32][32][128]
    unsigned short* d2    = d1 + 4194304;      // [B][32][32][64]
    unsigned short* f1o   = d2 + 2097152;      // [B][64][64][64]
    unsigned short* wT1   = f1o + 8388608;     // 221,184 (swizzled images)
    unsigned short* wT2   = wT1 + 221184;      // 73,728
    unsigned short* wTf1  = wT2 + 73728;       // 55,296
    unsigned short* wTf2  = wTf1 + 55296;      // 18,432
    unsigned short* wE2   = wTf2 + 18432;      // 13,312
    unsigned short* wE3   = wE2 + 13312;       // 9,216
    unsigned short* zbuf  = wE3 + 9216;        // 16B zero granule

    const int T = 256;

    // 1. conv1 (512 blocks) + weight prep (1528 blocks) + zerobuf
    conv1_prep<<<2040, T, 0, stream>>>(frameA, frameB, w1, b1, fineN, part1,
                                       wc1, wc2, wf1, wf2, w2, w3,
                                       wT1, wT2, wTf1, wTf2, wE2, wE3, zbuf);

    // 2. conv2s: BN1 applied at staging; emits pre-BN2 + part2
    conv2s_mfma<<<dim3(8, 1, 64), T, 0, stream>>>(fineN, wE2, b2, h2bf,
                                                  part1, g1, be1, part2);

    // 3. conv3: BN2 applied at staging; f32 out + part3
    conv3x3_mfma<32, 32, 32, 8, 0, 3, 2><<<dim3(8, 1, 64), T, 0, stream>>>(
        h2bf, nullptr, wE3, b3, (unsigned short*)c3N, nullptr, nullptr, nullptr,
        part2, g2, be2, part3, zbuf);

    // 4. BN3 finalize + lrelu + L2-norm -> coarseN
    bn3_l2n_nhwc<<<256, T, 0, stream>>>(c3N, part3, g3, be3, coarseN);

    // 5. correlation (register+shfl, 2048 blocks)
    corr_split<<<dim3(32, BATCH, 2), T, 0, stream>>>(coarseN, costN);

    // 6-9. decoder
    conv3x3_mfma<192, 128, 32, 8, 0, 0, 0><<<dim3(8, 2, BATCH), T, 0, stream>>>(
        costN, nullptr, wT1, bc1, d1, nullptr, nullptr, nullptr,
        nullptr, nullptr, nullptr, nullptr, zbuf);
    conv3x3_mfma<128, 64, 32, 4, 0, 0, 0><<<dim3(16, 1, BATCH), T, 0, stream>>>(
        d1, nullptr, wT2, bc2, d2, nullptr, nullptr, nullptr,
        nullptr, nullptr, nullptr, nullptr, zbuf);
    conv3x3_mfma<96, 64, 64, 8, 1, 0, 1><<<dim3(32, 1, BATCH), T, 0, stream>>>(
        d2, fineN, wTf1, bf1, f1o, nullptr, nullptr, nullptr,
        part1, g1, be1, nullptr, zbuf);
    conv3x3_mfma<64, 32, 64, 16, 0, 2, 0><<<dim3(16, 1, BATCH), T, 0, stream>>>(
        f1o, nullptr, wTf2, bf2, nullptr, (float*)d_out, wo, bo,
        nullptr, nullptr, nullptr, nullptr, zbuf);
}

// Round 17
// 168.600 us; speedup vs baseline: 1.0652x; 1.0652x over previous
//
#include <hip/hip_runtime.h>

typedef __attribute__((ext_vector_type(4))) float f32x4;
typedef __attribute__((ext_vector_type(8))) short bf16x8;

#define BN_EPS 1e-5f
constexpr int BATCH = 32;

static inline int cdiv(int a, int b) { return (a + b - 1) / b; }

__device__ __forceinline__ float lrelu(float v) { return v > 0.f ? v : 0.1f * v; }

__device__ __forceinline__ unsigned short f2bf(float f) {
    unsigned u = __float_as_uint(f);
    u = (u + 0x7FFFu + ((u >> 16) & 1u)) >> 16;
    return (unsigned short)u;
}
__device__ __forceinline__ float bf2f(unsigned short s) {
    return __uint_as_float(((unsigned)s) << 16);
}

// LDS XOR swizzles (elem units, preserve 16B store granules)
#define SWZ(e)  ((e) ^ ((((e) >> 6) & 3) << 3))
#define CSWZ(c, w) ((c) ^ (((w) & 7) << 2))

// async global->LDS, 16B per lane, wave-uniform LDS base (HW adds lane*16)
__device__ __forceinline__ void gload16(const unsigned short* g, unsigned short* l)
{
    __builtin_amdgcn_global_load_lds(
        (const __attribute__((address_space(1))) void*)g,
        (__attribute__((address_space(3))) void*)l,
        16, 0, 0);
}

// ---------------------------------------------------------------------------
// Per-block finalize of BN partials -> LDS stats (mean, rsqrt). Deterministic.
// ---------------------------------------------------------------------------
template<int C, int NS>
__device__ __forceinline__ void finalize_stats(const float2* __restrict__ part, int f,
                                               float inv, float* sstats)
{
    __shared__ float2 red[256];
    int t = threadIdx.x;
    int c = t % C, k = t / C;
    float s1 = 0.f, s2 = 0.f;
    for (int q = k; q < NS; q += 256 / C) {
        float2 p = part[(size_t)(f * C + c) * NS + q];
        s1 += p.x; s2 += p.y;
    }
    red[t] = make_float2(s1, s2);
    __syncthreads();
    for (int off = 128; off >= C; off >>= 1) {
        if (t < off) { red[t].x += red[t + off].x; red[t].y += red[t + off].y; }
        __syncthreads();
    }
    if (t < C) {
        float m = red[t].x * inv;
        float var = red[t].y * inv - m * m;
        sstats[2 * t]     = m;
        sstats[2 * t + 1] = rsqrtf(var + BN_EPS);
    }
    __syncthreads();
}

// ---------------------------------------------------------------------------
// Merged: encoder conv1 (blocks 0..511) + weight prep (blocks 512..2039).
// Weights written as pre-swizzled images: image[y] = orig[SWZ(y)].
// ---------------------------------------------------------------------------
__global__ __launch_bounds__(256) void conv1_prep(
    const float* __restrict__ fA, const float* __restrict__ fB,
    const float* __restrict__ w, const float* __restrict__ bias,
    unsigned short* __restrict__ outN, float2* __restrict__ part1,
    const float* wd1, const float* wd2, const float* wd3, const float* wd4,
    const float* wE2s, const float* wE3s,
    unsigned short* d1, unsigned short* d2, unsigned short* d3,
    unsigned short* d4, unsigned short* dE2, unsigned short* dE3,
    unsigned short* zb)
{
    const int gid = blockIdx.x;
    if (gid >= 512) {
        if (gid == 512 && threadIdx.x == 0) {
            int4 z = {0, 0, 0, 0};
            *(int4*)zb = z;
        }
        int idx = (gid - 512) * 256 + threadIdx.x;
        if (idx < 368640) {
            const float* src; unsigned short* dst; int MB, NOCB, CINS, COUT;
            if (idx < 221184)      { src = wd1; dst = d1; MB = 64; NOCB = 2; CINS = 169; COUT = 128; }
            else if (idx < 294912) { src = wd2; dst = d2; MB = 64; NOCB = 1; CINS = 128; COUT = 64; idx -= 221184; }
            else if (idx < 350208) { src = wd3; dst = d3; MB = 64; NOCB = 1; CINS = 96;  COUT = 64; idx -= 294912; }
            else                   { src = wd4; dst = d4; MB = 32; NOCB = 1; CINS = 64;  COUT = 32; idx -= 350208; }
            int lid = idx;
            int IMG = 9 * MB * 32;
            int chunk = lid / (NOCB * IMG);
            int r = lid % (NOCB * IMG);
            int ocb = r / IMG;
            int y = r % IMG;
            int z = SWZ(y);
            int row = z >> 5;
            int tap = (MB == 64) ? (row >> 6) : (row >> 5);
            int oc  = ocb * MB + (row & (MB - 1));
            int ic  = chunk * 32 + (z & 31);
            float v = (ic < CINS) ? src[((size_t)oc * CINS + ic) * 9 + tap] : 0.f;
            dst[lid] = f2bf(v);
        } else if (idx < 381952) {
            int lid = idx - 368640;
            int z = SWZ(lid);
            int row = z >> 5;
            int slot = row >> 5, ocr = row & 31;
            int c = z & 31;
            int tap = 2 * slot + (c >= 16 ? 1 : 0);
            int ic = c & 15;
            float v = (tap < 25) ? wE2s[((size_t)ocr * 16 + ic) * 25 + tap] : 0.f;
            dE2[lid] = f2bf(v);
        } else if (idx < 391168) {
            int lid = idx - 381952;
            int z = SWZ(lid);
            int row = z >> 5;
            int tap = row >> 5, ocr = row & 31;
            int ic = z & 31;
            dE3[lid] = f2bf(wE3s[((size_t)ocr * 32 + ic) * 9 + tap]);
        }
        return;
    }

    __shared__ float s_in[38][40];
    __shared__ float s_w[49][8];
    __shared__ float2 red1[4][8];

    const int tid = threadIdx.x;
    const int tx = tid & 15, ty = tid >> 4;
    const int tile = gid & 3;
    const int ocbase = ((gid >> 2) & 1) * 8;
    const int n = gid >> 3;
    const int x0 = (tile & 1) << 5;
    const int y0 = (tile >> 1) << 5;
    const float* in = (n < BATCH) ? (fA + (size_t)n * 4096) : (fB + (size_t)(n - BATCH) * 4096);

    for (int t = tid; t < 49 * 8; t += 256) {
        int oc = t & 7, k = t >> 3;
        s_w[k][oc] = w[(ocbase + oc) * 49 + k];
    }
    for (int t = tid; t < 38 * 38; t += 256) {
        int y = t / 38, x = t - (t / 38) * 38;
        int gy = y0 + y - 3, gx = x0 + x - 3;
        float v = 0.f;
        if ((unsigned)gy < 64u && (unsigned)gx < 64u) v = in[gy * 64 + gx];
        s_in[y][x] = v;
    }
    __syncthreads();

    float acc[8][4];
    #pragma unroll
    for (int oc = 0; oc < 8; ++oc) {
        float bv = bias[ocbase + oc];
        acc[oc][0] = bv; acc[oc][1] = bv; acc[oc][2] = bv; acc[oc][3] = bv;
    }
    #pragma unroll
    for (int kh = 0; kh < 7; ++kh) {
        #pragma unroll
        for (int kw = 0; kw < 7; ++kw) {
            float i00 = s_in[ty + kh][tx + kw];
            float i01 = s_in[ty + kh][tx + 16 + kw];
            float i10 = s_in[ty + 16 + kh][tx + kw];
            float i11 = s_in[ty + 16 + kh][tx + 16 + kw];
            #pragma unroll
            for (int oc = 0; oc < 8; ++oc) {
                float wv = s_w[kh * 7 + kw][oc];
                acc[oc][0] = fmaf(i00, wv, acc[oc][0]);
                acc[oc][1] = fmaf(i01, wv, acc[oc][1]);
                acc[oc][2] = fmaf(i10, wv, acc[oc][2]);
                acc[oc][3] = fmaf(i11, wv, acc[oc][3]);
            }
        }
    }
    #pragma unroll
    for (int i = 0; i < 2; ++i)
        #pragma unroll
        for (int j = 0; j < 2; ++j) {
            int k = i * 2 + j;
            int oy = y0 + ty + i * 16, ox = x0 + tx + j * 16;
            ushort4 p0, p1;
            p0.x = f2bf(acc[0][k]); p0.y = f2bf(acc[1][k]);
            p0.z = f2bf(acc[2][k]); p0.w = f2bf(acc[3][k]);
            p1.x = f2bf(acc[4][k]); p1.y = f2bf(acc[5][k]);
            p1.z = f2bf(acc[6][k]); p1.w = f2bf(acc[7][k]);
            unsigned short* dst = outN + ((size_t)n * 4096 + oy * 64 + ox) * 16 + ocbase;
            *(ushort4*)dst = p0;
            *(ushort4*)(dst + 4) = p1;
        }
    float v1[8], v2[8];
    #pragma unroll
    for (int oc = 0; oc < 8; ++oc) {
        v1[oc] = acc[oc][0] + acc[oc][1] + acc[oc][2] + acc[oc][3];
        v2[oc] = acc[oc][0] * acc[oc][0] + acc[oc][1] * acc[oc][1]
               + acc[oc][2] * acc[oc][2] + acc[oc][3] * acc[oc][3];
    }
    #pragma unroll
    for (int off = 32; off > 0; off >>= 1)
        #pragma unroll
        for (int oc = 0; oc < 8; ++oc) {
            v1[oc] += __shfl_down(v1[oc], off);
            v2[oc] += __shfl_down(v2[oc], off);
        }
    int wid = tid >> 6, lane = tid & 63;
    if (lane == 0)
        #pragma unroll
        for (int oc = 0; oc < 8; ++oc) red1[wid][oc] = make_float2(v1[oc], v2[oc]);
    __syncthreads();
    if (tid < 8) {
        float2 s = red1[0][tid];
        #pragma unroll
        for (int q = 1; q < 4; ++q) { s.x += red1[q][tid].x; s.y += red1[q][tid].y; }
        int f = n >> 5, slot = tile * 32 + (n & 31);      // NS=128
        part1[(size_t)(f * 16 + ocbase + tid) * 128 + slot] = s;
    }
}

// ---------------------------------------------------------------------------
// MFMA implicit-GEMM 3x3 pad-1 conv, NHWC bf16 in, fp32 accum.
// Weights: pre-swizzled images via global_load_lds. Inputs: async too when
// no BN-on-stage. OM: 0 bf16+lrelu; 1 f32; 2 lrelu + fused 1x1 (32->2) via
// shfl-reduce -> dout NCHW (MB=32); 3 f32 + BN partials.
// MODE 1 (f1): ch0-63 = upsample2x(d2) [async], 64-95 = skip w/ BN1 [VGPR].
// INBN: 0 none; 1 BN1 on skip channels; 2 BN on all input channels.
// ---------------------------------------------------------------------------
template<int CIN, int COUT, int H, int TH, int MODE, int OM, int INBN>
__global__ __launch_bounds__(256) void conv3x3_mfma(
    const unsigned short* __restrict__ in,
    const unsigned short* __restrict__ in2,
    const unsigned short* __restrict__ wT,
    const float* __restrict__ bias,
    unsigned short* __restrict__ out,
    float* __restrict__ dout,
    const float* __restrict__ w1x1,
    const float* __restrict__ b1x1,
    const float2* __restrict__ partIn,
    const float* __restrict__ gIn,
    const float* __restrict__ beIn,
    float2* __restrict__ partOut,
    const unsigned short* __restrict__ zb)
{
    constexpr int MB = (COUT >= 64) ? 64 : COUT;
    constexpr int MFRAGS = MB / 16;
    constexpr int WM = 2;
    constexpr int MW = MFRAGS / WM;
    constexpr int NW = 4 / MW;
    constexpr int WN = TH / NW;
    constexpr int NOCB = COUT / MB;
    constexpr int WIMG = 9 * MB * 32;
    constexpr int WTOT = WIMG / 512;
    constexpr int SIN_ELEMS = (TH + 2) * 18 * 32;
    constexpr int SIN_PAD = ((SIN_ELEMS + 511) / 512) * 512;
    constexpr int ITOT = SIN_PAD / 512;
    constexpr int NP = (TH + 2) * 18;     // valid granule-positions

    __shared__ unsigned short s_w[WIMG];
    __shared__ unsigned short s_in[SIN_PAD];
    __shared__ float sstIn[64];

    const int tid  = threadIdx.x;
    const int wid  = tid >> 6;
    const int lane = tid & 63;
    const int l15  = lane & 15;
    const int kg   = lane >> 4;
    constexpr int TILESX = H / 16;
    const int bx = blockIdx.x;
    const int x0 = (bx % TILESX) * 16;
    const int y0 = (bx / TILESX) * TH;
    const int ocbase = blockIdx.y * MB;
    const int n = blockIdx.z;

    const int mw = wid % MW;
    const int nw = wid / MW;

    if constexpr (INBN == 1)
        finalize_stats<32, 128>(partIn, 0, 1.f / (32.f * 4096.f), sstIn);
    if constexpr (INBN == 2)
        finalize_stats<32, 256>(partIn, n >> 5, 1.f / (32.f * 1024.f), sstIn);

    f32x4 acc[WM][WN];
    #pragma unroll
    for (int i = 0; i < WM; ++i) {
        #pragma unroll
        for (int r = 0; r < 4; ++r) {
            float bv = bias[ocbase + (mw * WM + i) * 16 + kg * 4 + r];
            #pragma unroll
            for (int j = 0; j < WN; ++j) acc[i][j][r] = bv;
        }
    }

    for (int c0 = 0; c0 < CIN; c0 += 32) {
        // async weight image copy (linear; values land pre-swizzled)
        {
            const unsigned short* wsrc = wT + ((size_t)((c0 >> 5) * NOCB + blockIdx.y)) * WIMG;
            for (int i = wid; i < WTOT; i += 4)
                gload16(wsrc + i * 512 + lane * 8, &s_w[i * 512]);
        }
        if constexpr (MODE == 0 && INBN == 0) {
            for (int i = wid; i < ITOT; i += 4) {
                int L = i * 512 + lane * 8;
                int z = SWZ(L);
                int p = z >> 5;
                int y = p / 18, x = p - y * 18;
                int gy = y0 - 1 + y, gx = x0 - 1 + x;
                const unsigned short* src = zb;
                if (p < NP && (unsigned)gy < (unsigned)H && (unsigned)gx < (unsigned)H)
                    src = &in[((size_t)(n * H + gy) * H + gx) * CIN + c0 + (z & 31)];
                gload16(src, &s_in[i * 512]);
            }
        } else if constexpr (MODE == 1) {
            if (c0 < 64) {
                for (int i = wid; i < ITOT; i += 4) {
                    int L = i * 512 + lane * 8;
                    int z = SWZ(L);
                    int p = z >> 5;
                    int y = p / 18, x = p - y * 18;
                    int gy = y0 - 1 + y, gx = x0 - 1 + x;
                    const unsigned short* src = zb;
                    if (p < NP && (unsigned)gy < 64u && (unsigned)gx < 64u)
                        src = &in[((size_t)(n * 32 + (gy >> 1)) * 32 + (gx >> 1)) * 64 + c0 + (z & 31)];
                    gload16(src, &s_in[i * 512]);
                }
            } else {
                for (int t = tid; t < NP * 4; t += 256) {
                    int sub = t & 3;
                    int p = t >> 2;
                    int y = p / 18, x = p - y * 18;
                    int gy = y0 - 1 + y, gx = x0 - 1 + x;
                    int4 v = {0, 0, 0, 0};
                    if ((unsigned)gy < 64u && (unsigned)gx < 64u) {
                        int f  = sub >> 1;
                        int cc = (sub & 1) * 8;
                        v = *(const int4*)&in2[((size_t)((f * BATCH + n) * 64 + gy) * 64 + gx) * 16 + cc];
                        unsigned short* e = (unsigned short*)&v;
                        #pragma unroll
                        for (int k = 0; k < 8; ++k) {
                            int gch = f * 16 + cc + k;
                            float xv = bf2f(e[k]);
                            e[k] = f2bf(lrelu((xv - sstIn[2 * gch]) * sstIn[2 * gch + 1]
                                              * gIn[cc + k] + beIn[cc + k]));
                        }
                    }
                    *(int4*)&s_in[SWZ(p * 32 + sub * 8)] = v;
                }
            }
        } else {
            for (int t = tid; t < NP * 4; t += 256) {
                int sub = t & 3;
                int p = t >> 2;
                int y = p / 18, x = p - y * 18;
                int gy = y0 - 1 + y, gx = x0 - 1 + x;
                int4 v = {0, 0, 0, 0};
                if ((unsigned)gy < (unsigned)H && (unsigned)gx < (unsigned)H) {
                    v = *(const int4*)&in[((size_t)(n * H + gy) * H + gx) * CIN + c0 + sub * 8];
                    if constexpr (INBN == 2) {
                        unsigned short* e = (unsigned short*)&v;
                        #pragma unroll
                        for (int k = 0; k < 8; ++k) {
                            int c = c0 + sub * 8 + k;
                            float xv = bf2f(e[k]);
                            e[k] = f2bf(lrelu((xv - sstIn[2 * c]) * sstIn[2 * c + 1] * gIn[c] + beIn[c]));
                        }
                    }
                }
                *(int4*)&s_in[SWZ(p * 32 + sub * 8)] = v;
            }
        }
        __syncthreads();   // drains vmcnt (incl. global_load_lds) + lgkm

        #pragma unroll
        for (int tap = 0; tap < 9; ++tap) {
            const int kh = tap / 3, kw = tap - (tap / 3) * 3;
            bf16x8 a[WM], b[WN];
            #pragma unroll
            for (int i = 0; i < WM; ++i) {
                int mf = mw * WM + i;
                a[i] = *(const bf16x8*)&s_w[SWZ((tap * MB + mf * 16 + l15) * 32 + kg * 8)];
            }
            #pragma unroll
            for (int j = 0; j < WN; ++j) {
                int nf = nw * WN + j;
                b[j] = *(const bf16x8*)&s_in[SWZ(((nf + kh) * 18 + l15 + kw) * 32 + kg * 8)];
            }
            #pragma unroll
            for (int i = 0; i < WM; ++i)
                #pragma unroll
                for (int j = 0; j < WN; ++j)
                    acc[i][j] = __builtin_amdgcn_mfma_f32_16x16x32_bf16(a[i], b[j], acc[i][j], 0, 0, 0);
        }
        __syncthreads();
    }

    if constexpr (OM == 2) {
        // fused 1x1 (32->2): per-lane partials over its 8 oc, shfl-reduce
        // across kg (lanes ^16, ^32). No LDS round-trip, dot on f32 accs.
        float w0l[8], w1l[8];
        #pragma unroll
        for (int i = 0; i < WM; ++i)
            #pragma unroll
            for (int r = 0; r < 4; ++r) {
                int oc = i * 16 + kg * 4 + r;
                w0l[i * 4 + r] = w1x1[oc];
                w1l[i * 4 + r] = w1x1[32 + oc];
            }
        #pragma unroll
        for (int j = 0; j < WN; ++j) {
            float s0 = 0.f, s1 = 0.f;
            #pragma unroll
            for (int i = 0; i < WM; ++i)
                #pragma unroll
                for (int r = 0; r < 4; ++r) {
                    float xv = lrelu(acc[i][j][r]);
                    s0 = fmaf(xv, w0l[i * 4 + r], s0);
                    s1 = fmaf(xv, w1l[i * 4 + r], s1);
                }
            s0 += __shfl_xor(s0, 16); s0 += __shfl_xor(s0, 32);
            s1 += __shfl_xor(s1, 16); s1 += __shfl_xor(s1, 32);
            if (kg == 0) {
                int gy = y0 + nw * WN + j, gx = x0 + l15;
                dout[((size_t)n * 2) * 4096 + gy * 64 + gx]     = s0 + b1x1[0];
                dout[((size_t)n * 2 + 1) * 4096 + gy * 64 + gx] = s1 + b1x1[1];
            }
        }
    } else {
        #pragma unroll
        for (int i = 0; i < WM; ++i) {
            int oc = ocbase + (mw * WM + i) * 16 + kg * 4;
            #pragma unroll
            for (int j = 0; j < WN; ++j) {
                int nf = nw * WN + j;
                int gy = y0 + nf, gx = x0 + l15;
                size_t base = ((size_t)(n * H + gy) * H + gx) * COUT + oc;
                if (OM == 0) {
                    ushort4 pk;
                    pk.x = f2bf(lrelu(acc[i][j][0]));
                    pk.y = f2bf(lrelu(acc[i][j][1]));
                    pk.z = f2bf(lrelu(acc[i][j][2]));
                    pk.w = f2bf(lrelu(acc[i][j][3]));
                    *(ushort4*)&out[base] = pk;
                } else {
                    *(f32x4*)&((float*)out)[base] = acc[i][j];
                }
            }
        }
    }

    if constexpr (OM == 3) {
        __shared__ float2 redC[4][4][8];
        float t1[2][4], t2[2][4];
        #pragma unroll
        for (int i = 0; i < 2; ++i)
            #pragma unroll
            for (int r = 0; r < 4; ++r) {
                float v0 = acc[i][0][r], v1 = acc[i][1][r];
                t1[i][r] = v0 + v1;
                t2[i][r] = v0 * v0 + v1 * v1;
            }
        #pragma unroll
        for (int off = 8; off > 0; off >>= 1)
            #pragma unroll
            for (int i = 0; i < 2; ++i)
                #pragma unroll
                for (int r = 0; r < 4; ++r) {
                    t1[i][r] += __shfl_down(t1[i][r], off);
                    t2[i][r] += __shfl_down(t2[i][r], off);
                }
        if (l15 == 0) {
            #pragma unroll
            for (int i = 0; i < 2; ++i)
                #pragma unroll
                for (int r = 0; r < 4; ++r)
                    redC[nw][kg][i * 4 + r] = make_float2(t1[i][r], t2[i][r]);
        }
        __syncthreads();
        if (tid < 32) {
            int oc = tid;
            int i = oc >> 4, kq = (oc & 15) >> 2, r = oc & 3;
            float2 s = redC[0][kq][i * 4 + r];
            #pragma unroll
            for (int q = 1; q < 4; ++q) {
                float2 p = redC[q][kq][i * 4 + r];
                s.x += p.x; s.y += p.y;
            }
            int f = n >> 5, slot = bx * 32 + (n & 31);   // NS=256
            partOut[(size_t)(f * 32 + oc) * 256 + slot] = s;
        }
    }
}

// ---------------------------------------------------------------------------
// Encoder conv2 (MFMA): 5x5 s2 pad2, 16->32. BN1 applied at staging.
// ---------------------------------------------------------------------------
__global__ __launch_bounds__(256) void conv2s_mfma(
    const unsigned short* __restrict__ in, const unsigned short* __restrict__ wS,
    const float* __restrict__ bias, unsigned short* __restrict__ outN,
    const float2* __restrict__ part1, const float* __restrict__ g1,
    const float* __restrict__ be1, float2* __restrict__ part2)
{
    __shared__ unsigned short s_w[13 * 32 * 32];
    __shared__ unsigned short s_in[20 * 36 * 16];
    __shared__ float2 redC[4][4][8];
    __shared__ float sst[32];

    const int tid = threadIdx.x;
    const int nw  = tid >> 6;
    const int lane = tid & 63;
    const int l15 = lane & 15;
    const int kg  = lane >> 4;
    const int x0 = (blockIdx.x & 1) * 16;
    const int y0 = (blockIdx.x >> 1) * 8;
    const int n  = blockIdx.z;

    for (int i = nw; i < 26; i += 4)
        gload16(wS + i * 512 + lane * 8, &s_w[i * 512]);

    finalize_stats<16, 128>(part1, n >> 5, 1.f / (32.f * 4096.f), sst);

    f32x4 acc[2][2];
    #pragma unroll
    for (int i = 0; i < 2; ++i) {
        #pragma unroll
        for (int r = 0; r < 4; ++r) {
            float bv = bias[i * 16 + kg * 4 + r];
            acc[i][0][r] = bv; acc[i][1][r] = bv;
        }
    }

    for (int t = tid; t < 1440; t += 256) {
        int sub = t & 1, p = t >> 1;
        int y = p / 36, x = p - y * 36;
        int gy = 2 * y0 - 2 + y, gx = 2 * x0 - 2 + x;
        int4 v = {0, 0, 0, 0};
        if ((unsigned)gy < 64u && (unsigned)gx < 64u) {
            v = *(const int4*)&in[((size_t)(n * 64 + gy) * 64 + gx) * 16 + sub * 8];
            unsigned short* e = (unsigned short*)&v;
            #pragma unroll
            for (int k = 0; k < 8; ++k) {
                int c = sub * 8 + k;
                float xv = bf2f(e[k]);
                e[k] = f2bf(lrelu((xv - sst[2 * c]) * sst[2 * c + 1] * g1[c] + be1[c]));
            }
        }
        *(int4*)&s_in[SWZ((y * 36 + x) * 16 + sub * 8)] = v;
    }
    __syncthreads();

    #pragma unroll
    for (int s = 0; s < 13; ++s) {
        int tA = 2 * s, tB = 2 * s + 1;
        int khA = tA / 5, kwA = tA % 5;
        int khB = tB / 5, kwB = tB % 5;
        int kh = (kg < 2) ? khA : khB;
        int kw = (kg < 2) ? kwA : kwB;
        int co = (kg & 1) * 8;
        bf16x8 a[2], b[2];
        a[0] = *(const bf16x8*)&s_w[SWZ((s * 32 + l15) * 32 + kg * 8)];
        a[1] = *(const bf16x8*)&s_w[SWZ((s * 32 + 16 + l15) * 32 + kg * 8)];
        #pragma unroll
        for (int j = 0; j < 2; ++j) {
            int py = nw * 2 + j;
            b[j] = *(const bf16x8*)&s_in[SWZ(((2 * py + kh) * 36 + 2 * l15 + kw) * 16 + co)];
        }
        acc[0][0] = __builtin_amdgcn_mfma_f32_16x16x32_bf16(a[0], b[0], acc[0][0], 0, 0, 0);
        acc[0][1] = __builtin_amdgcn_mfma_f32_16x16x32_bf16(a[0], b[1], acc[0][1], 0, 0, 0);
        acc[1][0] = __builtin_amdgcn_mfma_f32_16x16x32_bf16(a[1], b[0], acc[1][0], 0, 0, 0);
        acc[1][1] = __builtin_amdgcn_mfma_f32_16x16x32_bf16(a[1], b[1], acc[1][1], 0, 0, 0);
    }

    #pragma unroll
    for (int i = 0; i < 2; ++i)
        #pragma unroll
        for (int j = 0; j < 2; ++j) {
            int gy = y0 + nw * 2 + j, gx = x0 + l15;
            ushort4 pk;
            pk.x = f2bf(acc[i][j][0]); pk.y = f2bf(acc[i][j][1]);
            pk.z = f2bf(acc[i][j][2]); pk.w = f2bf(acc[i][j][3]);
            *(ushort4*)&outN[((size_t)(n * 32 + gy) * 32 + gx) * 32 + i * 16 + kg * 4] = pk;
        }

    float t1[2][4], t2[2][4];
    #pragma unroll
    for (int i = 0; i < 2; ++i)
        #pragma unroll
        for (int r = 0; r < 4; ++r) {
            float v0 = acc[i][0][r], v1 = acc[i][1][r];
            t1[i][r] = v0 + v1;
            t2[i][r] = v0 * v0 + v1 * v1;
        }
    #pragma unroll
    for (int off = 8; off > 0; off >>= 1)
        #pragma unroll
        for (int i = 0; i < 2; ++i)
            #pragma unroll
            for (int r = 0; r < 4; ++r) {
                t1[i][r] += __shfl_down(t1[i][r], off);
                t2[i][r] += __shfl_down(t2[i][r], off);
            }
    if (l15 == 0) {
        #pragma unroll
        for (int i = 0; i < 2; ++i)
            #pragma unroll
            for (int r = 0; r < 4; ++r)
                redC[nw][kg][i * 4 + r] = make_float2(t1[i][r], t2[i][r]);
    }
    __syncthreads();
    if (tid < 32) {
        int oc = tid;
        int i = oc >> 4, kq = (oc & 15) >> 2, r = oc & 3;
        float2 s = redC[0][kq][i * 4 + r];
        #pragma unroll
        for (int q = 1; q < 4; ++q) {
            float2 p = redC[q][kq][i * 4 + r];
            s.x += p.x; s.y += p.y;
        }
        int f = n >> 5, slot = blockIdx.x * 32 + (n & 31);
        part2[(size_t)(f * 32 + oc) * 256 + slot] = s;
    }
}

// ---------------------------------------------------------------------------
// BN3 finalize + lrelu + channel L2 norm. c3N f32 -> coarseN f32. Grid 256.
// ---------------------------------------------------------------------------
__global__ __launch_bounds__(256) void bn3_l2n_nhwc(const float* __restrict__ xN,
                             const float2* __restrict__ part3,
                             const float* __restrict__ g, const float* __restrict__ be,
                             float* __restrict__ outN)
{
    __shared__ float sst[64];
    int idx = blockIdx.x * blockDim.x + threadIdx.x;
    int f = idx >> 15;
    finalize_stats<32, 256>(part3, f, 1.f / (32.f * 1024.f), sst);
    const float* src = xN + (size_t)idx * 32;
    float v[32];
    float ss = 0.f;
    #pragma unroll
    for (int c = 0; c < 32; ++c) {
        float t = lrelu((src[c] - sst[2 * c]) * sst[2 * c + 1] * g[c] + be[c]);
        v[c] = t; ss += t * t;
    }
    float inv = 1.f / fmaxf(sqrtf(ss), 1e-12f);
    float* dst = outN + (size_t)idx * 32;
    #pragma unroll
    for (int c = 0; c < 32; ++c) dst[c] = v[c] * inv;
}

// ---------------------------------------------------------------------------
// Correlation, half-split (LDS-tiled): grid (32 h, B, 2). 38 KB -> 4 blk/CU.
// ---------------------------------------------------------------------------
__global__ __launch_bounds__(256) void corr_split(const float* __restrict__ xN,
                                                  unsigned short* __restrict__ cost)
{
    __shared__ float sA[32 * 32];
    __shared__ float sB[7][32 * 32];
    __shared__ unsigned short sC[32][96];

    const int h = blockIdx.x, b = blockIdx.y, half = blockIdx.z;
    const int ROWS = half ? 6 : 7;
    const float* Ab = xN + ((size_t)b * 1024 + h * 32) * 32;
    const float* Bb = xN + ((size_t)(BATCH + b) * 1024) * 32;

    {
        int t = threadIdx.x;
        int w = t >> 3, gr = t & 7;
        f32x4 v = *(const f32x4*)&Ab[w * 32 + gr * 4];
        *(f32x4*)&sA[w * 32 + CSWZ(gr * 4, w)] = v;
    }
    for (int t = threadIdx.x; t < ROWS * 256; t += 256) {
        int row = t >> 8, q = t & 255;
        int w = q >> 3, gr = q & 7;
        int gh = h + half * 7 + row - 6;
        f32x4 v = {0.f, 0.f, 0.f, 0.f};
        if ((unsigned)gh < 32u) v = *(const f32x4*)&Bb[((size_t)gh * 32 + w) * 32 + gr * 4];
        *(f32x4*)&sB[row][w * 32 + CSWZ(gr * 4, w)] = v;
    }
    __syncthreads();

    const int w = threadIdx.x & 31;
    const int gq = threadIdx.x >> 5;     // 0..7
    if (gq < ROWS) {
        f32x4 a[8];
        #pragma unroll
        for (int gr = 0; gr < 8; ++gr) a[gr] = *(const f32x4*)&sA[w * 32 + CSWZ(gr * 4, w)];
        #pragma unroll
        for (int dx = 0; dx < 13; ++dx) {
            int wb = w + dx - 6;
            float s = 0.f;
            if ((unsigned)wb < 32u) {
                #pragma unroll
                for (int gr = 0; gr < 8; ++gr) {
                    f32x4 bv = *(const f32x4*)&sB[gq][wb * 32 + CSWZ(gr * 4, wb)];
                    s += a[gr].x * bv.x + a[gr].y * bv.y + a[gr].z * bv.z + a[gr].w * bv.w;
                }
            }
            sC[w][gq * 13 + dx] = f2bf(s);
        }
    }
    __syncthreads();

    const int ND = ROWS * 13;            // 91 or 78
    for (int t = threadIdx.x; t < 32 * ND; t += 256) {
        int ww = t / ND;
        int d  = t - ww * ND;
        cost[((size_t)(b * 1024) + h * 32 + ww) * 192 + half * 91 + d] = sC[ww][d];
    }
}

// ---------------------------------------------------------------------------
extern "C" void kernel_launch(void* const* d_in, const int* in_sizes, int n_in,
                              void* d_out, int out_size, void* d_ws, size_t ws_size,
                              hipStream_t stream)
{
    const float* frameA = (const float*)d_in[0];
    const float* frameB = (const float*)d_in[1];
    const float* w1  = (const float*)d_in[2];
    const float* b1  = (const float*)d_in[3];
    const float* g1  = (const float*)d_in[4];
    const float* be1 = (const float*)d_in[5];
    const float* w2  = (const float*)d_in[6];
    const float* b2  = (const float*)d_in[7];
    const float* g2  = (const float*)d_in[8];
    const float* be2 = (const float*)d_in[9];
    const float* w3  = (const float*)d_in[10];
    const float* b3  = (const float*)d_in[11];
    const float* g3  = (const float*)d_in[12];
    const float* be3 = (const float*)d_in[13];
    const float* wc1 = (const float*)d_in[14];
    const float* bc1 = (const float*)d_in[15];
    const float* wc2 = (const float*)d_in[16];
    const float* bc2 = (const float*)d_in[17];
    const float* wf1 = (const float*)d_in[18];
    const float* bf1 = (const float*)d_in[19];
    const float* wf2 = (const float*)d_in[20];
    const float* bf2 = (const float*)d_in[21];
    const float* wo  = (const float*)d_in[22];
    const float* bo  = (const float*)d_in[23];

    // workspace layout
    float* ws      = (float*)d_ws;
    float* c3N     = ws;                              // [64][1024][32] f32  2,097,152
    float* coarseN = c3N + 2097152;                   // [64][1024][32] f32  2,097,152
    float2* part1  = (float2*)(coarseN + 2097152);    // 4096  float2 (BN1, NS=128)
    float2* part2  = part1 + 4096;                    // 16384 float2 (BN2, NS=256)
    float2* part3  = part2 + 16384;                   // 16384 float2 (BN3, NS=256)
    unsigned short* fineN = (unsigned short*)(part3 + 16384);  // [64][64][64][16] pre-BN
    unsigned short* h2bf  = fineN + 4194304;   // [64][32][32][32]  pre-BN2
    unsigned short* costN = h2bf + 2097152;    // [B][32][32][192]
    unsigned short* d1    = costN + 6291456;   // [B][32][32][128]
    unsigned short* d2    = d1 + 4194304;      // [B][32][32][64]
    unsigned short* f1o   = d2 + 2097152;      // [B][64][64][64]
    unsigned short* wT1   = f1o + 8388608;     // 221,184 (swizzled images)
    unsigned short* wT2   = wT1 + 221184;      // 73,728
    unsigned short* wTf1  = wT2 + 73728;       // 55,296
    unsigned short* wTf2  = wTf1 + 55296;      // 18,432
    unsigned short* wE2   = wTf2 + 18432;      // 13,312
    unsigned short* wE3   = wE2 + 13312;       // 9,216
    unsigned short* zbuf  = wE3 + 9216;        // 16B zero granule

    const int T = 256;

    // 1. conv1 (512 blocks) + weight prep (1528 blocks) + zerobuf
    conv1_prep<<<2040, T, 0, stream>>>(frameA, frameB, w1, b1, fineN, part1,
                                       wc1, wc2, wf1, wf2, w2, w3,
                                       wT1, wT2, wTf1, wTf2, wE2, wE3, zbuf);

    // 2. conv2s: BN1 applied at staging; emits pre-BN2 + part2
    conv2s_mfma<<<dim3(8, 1, 64), T, 0, stream>>>(fineN, wE2, b2, h2bf,
                                                  part1, g1, be1, part2);

    // 3. conv3: BN2 applied at staging; f32 out + part3
    conv3x3_mfma<32, 32, 32, 8, 0, 3, 2><<<dim3(8, 1, 64), T, 0, stream>>>(
        h2bf, nullptr, wE3, b3, (unsigned short*)c3N, nullptr, nullptr, nullptr,
        part2, g2, be2, part3, zbuf);

    // 4. BN3 finalize + lrelu + L2-norm -> coarseN
    bn3_l2n_nhwc<<<256, T, 0, stream>>>(c3N, part3, g3, be3, coarseN);

    // 5. correlation (half-split, 2048 blocks)
    corr_split<<<dim3(32, BATCH, 2), T, 0, stream>>>(coarseN, costN);

    // 6-9. decoder
    conv3x3_mfma<192, 128, 32, 8, 0, 0, 0><<<dim3(8, 2, BATCH), T, 0, stream>>>(
        costN, nullptr, wT1, bc1, d1, nullptr, nullptr, nullptr,
        nullptr, nullptr, nullptr, nullptr, zbuf);
    conv3x3_mfma<128, 64, 32, 4, 0, 0, 0><<<dim3(16, 1, BATCH), T, 0, stream>>>(
        d1, nullptr, wT2, bc2, d2, nullptr, nullptr, nullptr,
        nullptr, nullptr, nullptr, nullptr, zbuf);
    conv3x3_mfma<96, 64, 64, 8, 1, 0, 1><<<dim3(32, 1, BATCH), T, 0, stream>>>(
        d2, fineN, wTf1, bf1, f1o, nullptr, nullptr, nullptr,
        part1, g1, be1, nullptr, zbuf);
    conv3x3_mfma<64, 32, 64, 16, 0, 2, 0><<<dim3(16, 1, BATCH), T, 0, stream>>>(
        f1o, nullptr, wTf2, bf2, nullptr, (float*)d_out, wo, bo,
        nullptr, nullptr, nullptr, nullptr, zbuf);
}

// Round 18
// 168.118 us; speedup vs baseline: 1.0683x; 1.0029x over previous
//
#include <hip/hip_runtime.h>

typedef __attribute__((ext_vector_type(4))) float f32x4;
typedef __attribute__((ext_vector_type(8))) short bf16x8;

#define BN_EPS 1e-5f
constexpr int BATCH = 32;

static inline int cdiv(int a, int b) { return (a + b - 1) / b; }

__device__ __forceinline__ float lrelu(float v) { return v > 0.f ? v : 0.1f * v; }

__device__ __forceinline__ unsigned short f2bf(float f) {
    unsigned u = __float_as_uint(f);
    u = (u + 0x7FFFu + ((u >> 16) & 1u)) >> 16;
    return (unsigned short)u;
}
__device__ __forceinline__ float bf2f(unsigned short s) {
    return __uint_as_float(((unsigned)s) << 16);
}

// LDS XOR swizzles (elem units, preserve 16B store granules)
#define SWZ(e)  ((e) ^ ((((e) >> 6) & 3) << 3))
#define CSWZ(c, w) ((c) ^ (((w) & 7) << 2))

// async global->LDS, 16B per lane, wave-uniform LDS base (HW adds lane*16)
__device__ __forceinline__ void gload16(const unsigned short* g, unsigned short* l)
{
    __builtin_amdgcn_global_load_lds(
        (const __attribute__((address_space(1))) void*)g,
        (__attribute__((address_space(3))) void*)l,
        16, 0, 0);
}

// ---------------------------------------------------------------------------
// Per-block finalize of BN partials -> LDS stats (mean, rsqrt). Deterministic.
// ---------------------------------------------------------------------------
template<int C, int NS>
__device__ __forceinline__ void finalize_stats(const float2* __restrict__ part, int f,
                                               float inv, float* sstats)
{
    __shared__ float2 red[256];
    int t = threadIdx.x;
    int c = t % C, k = t / C;
    float s1 = 0.f, s2 = 0.f;
    for (int q = k; q < NS; q += 256 / C) {
        float2 p = part[(size_t)(f * C + c) * NS + q];
        s1 += p.x; s2 += p.y;
    }
    red[t] = make_float2(s1, s2);
    __syncthreads();
    for (int off = 128; off >= C; off >>= 1) {
        if (t < off) { red[t].x += red[t + off].x; red[t].y += red[t + off].y; }
        __syncthreads();
    }
    if (t < C) {
        float m = red[t].x * inv;
        float var = red[t].y * inv - m * m;
        sstats[2 * t]     = m;
        sstats[2 * t + 1] = rsqrtf(var + BN_EPS);
    }
    __syncthreads();
}

// ---------------------------------------------------------------------------
// Merged: encoder conv1 (blocks 0..511) + weight prep (blocks 512..2039).
// Weights written as pre-swizzled images: image[y] = orig[SWZ(y)].
// ---------------------------------------------------------------------------
__global__ __launch_bounds__(256) void conv1_prep(
    const float* __restrict__ fA, const float* __restrict__ fB,
    const float* __restrict__ w, const float* __restrict__ bias,
    unsigned short* __restrict__ outN, float2* __restrict__ part1,
    const float* wd1, const float* wd2, const float* wd3, const float* wd4,
    const float* wE2s, const float* wE3s,
    unsigned short* d1, unsigned short* d2, unsigned short* d3,
    unsigned short* d4, unsigned short* dE2, unsigned short* dE3,
    unsigned short* zb)
{
    const int gid = blockIdx.x;
    if (gid >= 512) {
        if (gid == 512 && threadIdx.x == 0) {
            int4 z = {0, 0, 0, 0};
            *(int4*)zb = z;
        }
        int idx = (gid - 512) * 256 + threadIdx.x;
        if (idx < 368640) {
            const float* src; unsigned short* dst; int MB, NOCB, CINS, COUT;
            if (idx < 221184)      { src = wd1; dst = d1; MB = 64; NOCB = 2; CINS = 169; COUT = 128; }
            else if (idx < 294912) { src = wd2; dst = d2; MB = 64; NOCB = 1; CINS = 128; COUT = 64; idx -= 221184; }
            else if (idx < 350208) { src = wd3; dst = d3; MB = 64; NOCB = 1; CINS = 96;  COUT = 64; idx -= 294912; }
            else                   { src = wd4; dst = d4; MB = 32; NOCB = 1; CINS = 64;  COUT = 32; idx -= 350208; }
            int lid = idx;
            int IMG = 9 * MB * 32;
            int chunk = lid / (NOCB * IMG);
            int r = lid % (NOCB * IMG);
            int ocb = r / IMG;
            int y = r % IMG;
            int z = SWZ(y);
            int row = z >> 5;
            int tap = (MB == 64) ? (row >> 6) : (row >> 5);
            int oc  = ocb * MB + (row & (MB - 1));
            int ic  = chunk * 32 + (z & 31);
            float v = (ic < CINS) ? src[((size_t)oc * CINS + ic) * 9 + tap] : 0.f;
            dst[lid] = f2bf(v);
        } else if (idx < 381952) {
            int lid = idx - 368640;
            int z = SWZ(lid);
            int row = z >> 5;
            int slot = row >> 5, ocr = row & 31;
            int c = z & 31;
            int tap = 2 * slot + (c >= 16 ? 1 : 0);
            int ic = c & 15;
            float v = (tap < 25) ? wE2s[((size_t)ocr * 16 + ic) * 25 + tap] : 0.f;
            dE2[lid] = f2bf(v);
        } else if (idx < 391168) {
            int lid = idx - 381952;
            int z = SWZ(lid);
            int row = z >> 5;
            int tap = row >> 5, ocr = row & 31;
            int ic = z & 31;
            dE3[lid] = f2bf(wE3s[((size_t)ocr * 32 + ic) * 9 + tap]);
        }
        return;
    }

    __shared__ float s_in[38][40];
    __shared__ float s_w[49][8];
    __shared__ float2 red1[4][8];

    const int tid = threadIdx.x;
    const int tx = tid & 15, ty = tid >> 4;
    const int tile = gid & 3;
    const int ocbase = ((gid >> 2) & 1) * 8;
    const int n = gid >> 3;
    const int x0 = (tile & 1) << 5;
    const int y0 = (tile >> 1) << 5;
    const float* in = (n < BATCH) ? (fA + (size_t)n * 4096) : (fB + (size_t)(n - BATCH) * 4096);

    for (int t = tid; t < 49 * 8; t += 256) {
        int oc = t & 7, k = t >> 3;
        s_w[k][oc] = w[(ocbase + oc) * 49 + k];
    }
    for (int t = tid; t < 38 * 38; t += 256) {
        int y = t / 38, x = t - (t / 38) * 38;
        int gy = y0 + y - 3, gx = x0 + x - 3;
        float v = 0.f;
        if ((unsigned)gy < 64u && (unsigned)gx < 64u) v = in[gy * 64 + gx];
        s_in[y][x] = v;
    }
    __syncthreads();

    float acc[8][4];
    #pragma unroll
    for (int oc = 0; oc < 8; ++oc) {
        float bv = bias[ocbase + oc];
        acc[oc][0] = bv; acc[oc][1] = bv; acc[oc][2] = bv; acc[oc][3] = bv;
    }
    #pragma unroll
    for (int kh = 0; kh < 7; ++kh) {
        #pragma unroll
        for (int kw = 0; kw < 7; ++kw) {
            float i00 = s_in[ty + kh][tx + kw];
            float i01 = s_in[ty + kh][tx + 16 + kw];
            float i10 = s_in[ty + 16 + kh][tx + kw];
            float i11 = s_in[ty + 16 + kh][tx + 16 + kw];
            #pragma unroll
            for (int oc = 0; oc < 8; ++oc) {
                float wv = s_w[kh * 7 + kw][oc];
                acc[oc][0] = fmaf(i00, wv, acc[oc][0]);
                acc[oc][1] = fmaf(i01, wv, acc[oc][1]);
                acc[oc][2] = fmaf(i10, wv, acc[oc][2]);
                acc[oc][3] = fmaf(i11, wv, acc[oc][3]);
            }
        }
    }
    #pragma unroll
    for (int i = 0; i < 2; ++i)
        #pragma unroll
        for (int j = 0; j < 2; ++j) {
            int k = i * 2 + j;
            int oy = y0 + ty + i * 16, ox = x0 + tx + j * 16;
            ushort4 p0, p1;
            p0.x = f2bf(acc[0][k]); p0.y = f2bf(acc[1][k]);
            p0.z = f2bf(acc[2][k]); p0.w = f2bf(acc[3][k]);
            p1.x = f2bf(acc[4][k]); p1.y = f2bf(acc[5][k]);
            p1.z = f2bf(acc[6][k]); p1.w = f2bf(acc[7][k]);
            unsigned short* dst = outN + ((size_t)n * 4096 + oy * 64 + ox) * 16 + ocbase;
            *(ushort4*)dst = p0;
            *(ushort4*)(dst + 4) = p1;
        }
    float v1[8], v2[8];
    #pragma unroll
    for (int oc = 0; oc < 8; ++oc) {
        v1[oc] = acc[oc][0] + acc[oc][1] + acc[oc][2] + acc[oc][3];
        v2[oc] = acc[oc][0] * acc[oc][0] + acc[oc][1] * acc[oc][1]
               + acc[oc][2] * acc[oc][2] + acc[oc][3] * acc[oc][3];
    }
    #pragma unroll
    for (int off = 32; off > 0; off >>= 1)
        #pragma unroll
        for (int oc = 0; oc < 8; ++oc) {
            v1[oc] += __shfl_down(v1[oc], off);
            v2[oc] += __shfl_down(v2[oc], off);
        }
    int wid = tid >> 6, lane = tid & 63;
    if (lane == 0)
        #pragma unroll
        for (int oc = 0; oc < 8; ++oc) red1[wid][oc] = make_float2(v1[oc], v2[oc]);
    __syncthreads();
    if (tid < 8) {
        float2 s = red1[0][tid];
        #pragma unroll
        for (int q = 1; q < 4; ++q) { s.x += red1[q][tid].x; s.y += red1[q][tid].y; }
        int f = n >> 5, slot = tile * 32 + (n & 31);      // NS=128
        part1[(size_t)(f * 16 + ocbase + tid) * 128 + slot] = s;
    }
}

// ---------------------------------------------------------------------------
// MFMA implicit-GEMM 3x3 pad-1 conv, NHWC bf16 in, fp32 accum.
// kw-major tap loop: B-fragments shared across kh (WN+2 rows per kw instead
// of 3*WN) -> hot-loop ds_reads 54 -> 36 per chunk.
// Weights: pre-swizzled images via global_load_lds. Inputs async when no
// BN-on-stage. OM: 0 bf16+lrelu; 1 f32; 2 lrelu+fused 1x1 -> dout; 3 f32+BN.
// ---------------------------------------------------------------------------
template<int CIN, int COUT, int H, int TH, int MODE, int OM, int INBN>
__global__ __launch_bounds__(256) void conv3x3_mfma(
    const unsigned short* __restrict__ in,
    const unsigned short* __restrict__ in2,
    const unsigned short* __restrict__ wT,
    const float* __restrict__ bias,
    unsigned short* __restrict__ out,
    float* __restrict__ dout,
    const float* __restrict__ w1x1,
    const float* __restrict__ b1x1,
    const float2* __restrict__ partIn,
    const float* __restrict__ gIn,
    const float* __restrict__ beIn,
    float2* __restrict__ partOut,
    const unsigned short* __restrict__ zb)
{
    constexpr int MB = (COUT >= 64) ? 64 : COUT;
    constexpr int MFRAGS = MB / 16;
    constexpr int WM = 2;
    constexpr int MW = MFRAGS / WM;
    constexpr int NW = 4 / MW;
    constexpr int WN = TH / NW;
    constexpr int NOCB = COUT / MB;
    constexpr int WIMG = 9 * MB * 32;
    constexpr int WTOT = WIMG / 512;
    constexpr int SIN_ELEMS = (TH + 2) * 18 * 32;
    constexpr int SIN_PAD = ((SIN_ELEMS + 511) / 512) * 512;
    constexpr int ITOT = SIN_PAD / 512;
    constexpr int NP = (TH + 2) * 18;     // valid granule-positions

    __shared__ unsigned short s_w[WIMG];
    __shared__ unsigned short s_in[SIN_PAD];
    __shared__ float sstIn[64];

    const int tid  = threadIdx.x;
    const int wid  = tid >> 6;
    const int lane = tid & 63;
    const int l15  = lane & 15;
    const int kg   = lane >> 4;
    constexpr int TILESX = H / 16;
    const int bx = blockIdx.x;
    const int x0 = (bx % TILESX) * 16;
    const int y0 = (bx / TILESX) * TH;
    const int ocbase = blockIdx.y * MB;
    const int n = blockIdx.z;

    const int mw = wid % MW;
    const int nw = wid / MW;

    if constexpr (INBN == 1)
        finalize_stats<32, 128>(partIn, 0, 1.f / (32.f * 4096.f), sstIn);
    if constexpr (INBN == 2)
        finalize_stats<32, 256>(partIn, n >> 5, 1.f / (32.f * 1024.f), sstIn);

    f32x4 acc[WM][WN];
    #pragma unroll
    for (int i = 0; i < WM; ++i) {
        #pragma unroll
        for (int r = 0; r < 4; ++r) {
            float bv = bias[ocbase + (mw * WM + i) * 16 + kg * 4 + r];
            #pragma unroll
            for (int j = 0; j < WN; ++j) acc[i][j][r] = bv;
        }
    }

    for (int c0 = 0; c0 < CIN; c0 += 32) {
        // async weight image copy (linear; values land pre-swizzled)
        {
            const unsigned short* wsrc = wT + ((size_t)((c0 >> 5) * NOCB + blockIdx.y)) * WIMG;
            for (int i = wid; i < WTOT; i += 4)
                gload16(wsrc + i * 512 + lane * 8, &s_w[i * 512]);
        }
        if constexpr (MODE == 0 && INBN == 0) {
            for (int i = wid; i < ITOT; i += 4) {
                int L = i * 512 + lane * 8;
                int z = SWZ(L);
                int p = z >> 5;
                int y = p / 18, x = p - y * 18;
                int gy = y0 - 1 + y, gx = x0 - 1 + x;
                const unsigned short* src = zb;
                if (p < NP && (unsigned)gy < (unsigned)H && (unsigned)gx < (unsigned)H)
                    src = &in[((size_t)(n * H + gy) * H + gx) * CIN + c0 + (z & 31)];
                gload16(src, &s_in[i * 512]);
            }
        } else if constexpr (MODE == 1) {
            if (c0 < 64) {
                for (int i = wid; i < ITOT; i += 4) {
                    int L = i * 512 + lane * 8;
                    int z = SWZ(L);
                    int p = z >> 5;
                    int y = p / 18, x = p - y * 18;
                    int gy = y0 - 1 + y, gx = x0 - 1 + x;
                    const unsigned short* src = zb;
                    if (p < NP && (unsigned)gy < 64u && (unsigned)gx < 64u)
                        src = &in[((size_t)(n * 32 + (gy >> 1)) * 32 + (gx >> 1)) * 64 + c0 + (z & 31)];
                    gload16(src, &s_in[i * 512]);
                }
            } else {
                for (int t = tid; t < NP * 4; t += 256) {
                    int sub = t & 3;
                    int p = t >> 2;
                    int y = p / 18, x = p - y * 18;
                    int gy = y0 - 1 + y, gx = x0 - 1 + x;
                    int4 v = {0, 0, 0, 0};
                    if ((unsigned)gy < 64u && (unsigned)gx < 64u) {
                        int f  = sub >> 1;
                        int cc = (sub & 1) * 8;
                        v = *(const int4*)&in2[((size_t)((f * BATCH + n) * 64 + gy) * 64 + gx) * 16 + cc];
                        unsigned short* e = (unsigned short*)&v;
                        #pragma unroll
                        for (int k = 0; k < 8; ++k) {
                            int gch = f * 16 + cc + k;
                            float xv = bf2f(e[k]);
                            e[k] = f2bf(lrelu((xv - sstIn[2 * gch]) * sstIn[2 * gch + 1]
                                              * gIn[cc + k] + beIn[cc + k]));
                        }
                    }
                    *(int4*)&s_in[SWZ(p * 32 + sub * 8)] = v;
                }
            }
        } else {
            for (int t = tid; t < NP * 4; t += 256) {
                int sub = t & 3;
                int p = t >> 2;
                int y = p / 18, x = p - y * 18;
                int gy = y0 - 1 + y, gx = x0 - 1 + x;
                int4 v = {0, 0, 0, 0};
                if ((unsigned)gy < (unsigned)H && (unsigned)gx < (unsigned)H) {
                    v = *(const int4*)&in[((size_t)(n * H + gy) * H + gx) * CIN + c0 + sub * 8];
                    if constexpr (INBN == 2) {
                        unsigned short* e = (unsigned short*)&v;
                        #pragma unroll
                        for (int k = 0; k < 8; ++k) {
                            int c = c0 + sub * 8 + k;
                            float xv = bf2f(e[k]);
                            e[k] = f2bf(lrelu((xv - sstIn[2 * c]) * sstIn[2 * c + 1] * gIn[c] + beIn[c]));
                        }
                    }
                }
                *(int4*)&s_in[SWZ(p * 32 + sub * 8)] = v;
            }
        }
        __syncthreads();   // drains vmcnt (incl. global_load_lds) + lgkm

        // kw-major tap loop: bx rows shared across kh (36 reads vs 54)
        #pragma unroll
        for (int kw = 0; kw < 3; ++kw) {
            bf16x8 bxr[WN + 2];
            #pragma unroll
            for (int m = 0; m < WN + 2; ++m) {
                int row = nw * WN + m;
                bxr[m] = *(const bf16x8*)&s_in[SWZ((row * 18 + l15 + kw) * 32 + kg * 8)];
            }
            #pragma unroll
            for (int kh = 0; kh < 3; ++kh) {
                const int tap = kh * 3 + kw;
                bf16x8 a[WM];
                #pragma unroll
                for (int i = 0; i < WM; ++i) {
                    int mf = mw * WM + i;
                    a[i] = *(const bf16x8*)&s_w[SWZ((tap * MB + mf * 16 + l15) * 32 + kg * 8)];
                }
                #pragma unroll
                for (int i = 0; i < WM; ++i)
                    #pragma unroll
                    for (int j = 0; j < WN; ++j)
                        acc[i][j] = __builtin_amdgcn_mfma_f32_16x16x32_bf16(a[i], bxr[j + kh], acc[i][j], 0, 0, 0);
            }
        }
        __syncthreads();
    }

    if constexpr (OM == 2) {
        // fused 1x1 (32->2): per-lane partials over its 8 oc, shfl-reduce
        // across kg (lanes ^16, ^32). No LDS round-trip, dot on f32 accs.
        float w0l[8], w1l[8];
        #pragma unroll
        for (int i = 0; i < WM; ++i)
            #pragma unroll
            for (int r = 0; r < 4; ++r) {
                int oc = i * 16 + kg * 4 + r;
                w0l[i * 4 + r] = w1x1[oc];
                w1l[i * 4 + r] = w1x1[32 + oc];
            }
        #pragma unroll
        for (int j = 0; j < WN; ++j) {
            float s0 = 0.f, s1 = 0.f;
            #pragma unroll
            for (int i = 0; i < WM; ++i)
                #pragma unroll
                for (int r = 0; r < 4; ++r) {
                    float xv = lrelu(acc[i][j][r]);
                    s0 = fmaf(xv, w0l[i * 4 + r], s0);
                    s1 = fmaf(xv, w1l[i * 4 + r], s1);
                }
            s0 += __shfl_xor(s0, 16); s0 += __shfl_xor(s0, 32);
            s1 += __shfl_xor(s1, 16); s1 += __shfl_xor(s1, 32);
            if (kg == 0) {
                int gy = y0 + nw * WN + j, gx = x0 + l15;
                dout[((size_t)n * 2) * 4096 + gy * 64 + gx]     = s0 + b1x1[0];
                dout[((size_t)n * 2 + 1) * 4096 + gy * 64 + gx] = s1 + b1x1[1];
            }
        }
    } else {
        #pragma unroll
        for (int i = 0; i < WM; ++i) {
            int oc = ocbase + (mw * WM + i) * 16 + kg * 4;
            #pragma unroll
            for (int j = 0; j < WN; ++j) {
                int nf = nw * WN + j;
                int gy = y0 + nf, gx = x0 + l15;
                size_t base = ((size_t)(n * H + gy) * H + gx) * COUT + oc;
                if (OM == 0) {
                    ushort4 pk;
                    pk.x = f2bf(lrelu(acc[i][j][0]));
                    pk.y = f2bf(lrelu(acc[i][j][1]));
                    pk.z = f2bf(lrelu(acc[i][j][2]));
                    pk.w = f2bf(lrelu(acc[i][j][3]));
                    *(ushort4*)&out[base] = pk;
                } else {
                    *(f32x4*)&((float*)out)[base] = acc[i][j];
                }
            }
        }
    }

    if constexpr (OM == 3) {
        __shared__ float2 redC[4][4][8];
        float t1[2][4], t2[2][4];
        #pragma unroll
        for (int i = 0; i < 2; ++i)
            #pragma unroll
            for (int r = 0; r < 4; ++r) {
                float v0 = acc[i][0][r], v1 = acc[i][1][r];
                t1[i][r] = v0 + v1;
                t2[i][r] = v0 * v0 + v1 * v1;
            }
        #pragma unroll
        for (int off = 8; off > 0; off >>= 1)
            #pragma unroll
            for (int i = 0; i < 2; ++i)
                #pragma unroll
                for (int r = 0; r < 4; ++r) {
                    t1[i][r] += __shfl_down(t1[i][r], off);
                    t2[i][r] += __shfl_down(t2[i][r], off);
                }
        if (l15 == 0) {
            #pragma unroll
            for (int i = 0; i < 2; ++i)
                #pragma unroll
                for (int r = 0; r < 4; ++r)
                    redC[nw][kg][i * 4 + r] = make_float2(t1[i][r], t2[i][r]);
        }
        __syncthreads();
        if (tid < 32) {
            int oc = tid;
            int i = oc >> 4, kq = (oc & 15) >> 2, r = oc & 3;
            float2 s = redC[0][kq][i * 4 + r];
            #pragma unroll
            for (int q = 1; q < 4; ++q) {
                float2 p = redC[q][kq][i * 4 + r];
                s.x += p.x; s.y += p.y;
            }
            int f = n >> 5, slot = bx * 32 + (n & 31);   // NS=256
            partOut[(size_t)(f * 32 + oc) * 256 + slot] = s;
        }
    }
}

// ---------------------------------------------------------------------------
// Encoder conv2 (MFMA): 5x5 s2 pad2, 16->32. BN1 applied at staging.
// ---------------------------------------------------------------------------
__global__ __launch_bounds__(256) void conv2s_mfma(
    const unsigned short* __restrict__ in, const unsigned short* __restrict__ wS,
    const float* __restrict__ bias, unsigned short* __restrict__ outN,
    const float2* __restrict__ part1, const float* __restrict__ g1,
    const float* __restrict__ be1, float2* __restrict__ part2)
{
    __shared__ unsigned short s_w[13 * 32 * 32];
    __shared__ unsigned short s_in[20 * 36 * 16];
    __shared__ float2 redC[4][4][8];
    __shared__ float sst[32];

    const int tid = threadIdx.x;
    const int nw  = tid >> 6;
    const int lane = tid & 63;
    const int l15 = lane & 15;
    const int kg  = lane >> 4;
    const int x0 = (blockIdx.x & 1) * 16;
    const int y0 = (blockIdx.x >> 1) * 8;
    const int n  = blockIdx.z;

    for (int i = nw; i < 26; i += 4)
        gload16(wS + i * 512 + lane * 8, &s_w[i * 512]);

    finalize_stats<16, 128>(part1, n >> 5, 1.f / (32.f * 4096.f), sst);

    f32x4 acc[2][2];
    #pragma unroll
    for (int i = 0; i < 2; ++i) {
        #pragma unroll
        for (int r = 0; r < 4; ++r) {
            float bv = bias[i * 16 + kg * 4 + r];
            acc[i][0][r] = bv; acc[i][1][r] = bv;
        }
    }

    for (int t = tid; t < 1440; t += 256) {
        int sub = t & 1, p = t >> 1;
        int y = p / 36, x = p - y * 36;
        int gy = 2 * y0 - 2 + y, gx = 2 * x0 - 2 + x;
        int4 v = {0, 0, 0, 0};
        if ((unsigned)gy < 64u && (unsigned)gx < 64u) {
            v = *(const int4*)&in[((size_t)(n * 64 + gy) * 64 + gx) * 16 + sub * 8];
            unsigned short* e = (unsigned short*)&v;
            #pragma unroll
            for (int k = 0; k < 8; ++k) {
                int c = sub * 8 + k;
                float xv = bf2f(e[k]);
                e[k] = f2bf(lrelu((xv - sst[2 * c]) * sst[2 * c + 1] * g1[c] + be1[c]));
            }
        }
        *(int4*)&s_in[SWZ((y * 36 + x) * 16 + sub * 8)] = v;
    }
    __syncthreads();

    #pragma unroll
    for (int s = 0; s < 13; ++s) {
        int tA = 2 * s, tB = 2 * s + 1;
        int khA = tA / 5, kwA = tA % 5;
        int khB = tB / 5, kwB = tB % 5;
        int kh = (kg < 2) ? khA : khB;
        int kw = (kg < 2) ? kwA : kwB;
        int co = (kg & 1) * 8;
        bf16x8 a[2], b[2];
        a[0] = *(const bf16x8*)&s_w[SWZ((s * 32 + l15) * 32 + kg * 8)];
        a[1] = *(const bf16x8*)&s_w[SWZ((s * 32 + 16 + l15) * 32 + kg * 8)];
        #pragma unroll
        for (int j = 0; j < 2; ++j) {
            int py = nw * 2 + j;
            b[j] = *(const bf16x8*)&s_in[SWZ(((2 * py + kh) * 36 + 2 * l15 + kw) * 16 + co)];
        }
        acc[0][0] = __builtin_amdgcn_mfma_f32_16x16x32_bf16(a[0], b[0], acc[0][0], 0, 0, 0);
        acc[0][1] = __builtin_amdgcn_mfma_f32_16x16x32_bf16(a[0], b[1], acc[0][1], 0, 0, 0);
        acc[1][0] = __builtin_amdgcn_mfma_f32_16x16x32_bf16(a[1], b[0], acc[1][0], 0, 0, 0);
        acc[1][1] = __builtin_amdgcn_mfma_f32_16x16x32_bf16(a[1], b[1], acc[1][1], 0, 0, 0);
    }

    #pragma unroll
    for (int i = 0; i < 2; ++i)
        #pragma unroll
        for (int j = 0; j < 2; ++j) {
            int gy = y0 + nw * 2 + j, gx = x0 + l15;
            ushort4 pk;
            pk.x = f2bf(acc[i][j][0]); pk.y = f2bf(acc[i][j][1]);
            pk.z = f2bf(acc[i][j][2]); pk.w = f2bf(acc[i][j][3]);
            *(ushort4*)&outN[((size_t)(n * 32 + gy) * 32 + gx) * 32 + i * 16 + kg * 4] = pk;
        }

    float t1[2][4], t2[2][4];
    #pragma unroll
    for (int i = 0; i < 2; ++i)
        #pragma unroll
        for (int r = 0; r < 4; ++r) {
            float v0 = acc[i][0][r], v1 = acc[i][1][r];
            t1[i][r] = v0 + v1;
            t2[i][r] = v0 * v0 + v1 * v1;
        }
    #pragma unroll
    for (int off = 8; off > 0; off >>= 1)
        #pragma unroll
        for (int i = 0; i < 2; ++i)
            #pragma unroll
            for (int r = 0; r < 4; ++r) {
                t1[i][r] += __shfl_down(t1[i][r], off);
                t2[i][r] += __shfl_down(t2[i][r], off);
            }
    if (l15 == 0) {
        #pragma unroll
        for (int i = 0; i < 2; ++i)
            #pragma unroll
            for (int r = 0; r < 4; ++r)
                redC[nw][kg][i * 4 + r] = make_float2(t1[i][r], t2[i][r]);
    }
    __syncthreads();
    if (tid < 32) {
        int oc = tid;
        int i = oc >> 4, kq = (oc & 15) >> 2, r = oc & 3;
        float2 s = redC[0][kq][i * 4 + r];
        #pragma unroll
        for (int q = 1; q < 4; ++q) {
            float2 p = redC[q][kq][i * 4 + r];
            s.x += p.x; s.y += p.y;
        }
        int f = n >> 5, slot = blockIdx.x * 32 + (n & 31);
        part2[(size_t)(f * 32 + oc) * 256 + slot] = s;
    }
}

// ---------------------------------------------------------------------------
// BN3 finalize + lrelu + channel L2 norm. c3N f32 -> coarseN f32. Grid 256.
// ---------------------------------------------------------------------------
__global__ __launch_bounds__(256) void bn3_l2n_nhwc(const float* __restrict__ xN,
                             const float2* __restrict__ part3,
                             const float* __restrict__ g, const float* __restrict__ be,
                             float* __restrict__ outN)
{
    __shared__ float sst[64];
    int idx = blockIdx.x * blockDim.x + threadIdx.x;
    int f = idx >> 15;
    finalize_stats<32, 256>(part3, f, 1.f / (32.f * 1024.f), sst);
    const float* src = xN + (size_t)idx * 32;
    float v[32];
    float ss = 0.f;
    #pragma unroll
    for (int c = 0; c < 32; ++c) {
        float t = lrelu((src[c] - sst[2 * c]) * sst[2 * c + 1] * g[c] + be[c]);
        v[c] = t; ss += t * t;
    }
    float inv = 1.f / fmaxf(sqrtf(ss), 1e-12f);
    float* dst = outN + (size_t)idx * 32;
    #pragma unroll
    for (int c = 0; c < 32; ++c) dst[c] = v[c] * inv;
}

// ---------------------------------------------------------------------------
// Correlation, half-split (LDS-tiled): grid (32 h, B, 2). 38 KB -> 4 blk/CU.
// ---------------------------------------------------------------------------
__global__ __launch_bounds__(256) void corr_split(const float* __restrict__ xN,
                                                  unsigned short* __restrict__ cost)
{
    __shared__ float sA[32 * 32];
    __shared__ float sB[7][32 * 32];
    __shared__ unsigned short sC[32][96];

    const int h = blockIdx.x, b = blockIdx.y, half = blockIdx.z;
    const int ROWS = half ? 6 : 7;
    const float* Ab = xN + ((size_t)b * 1024 + h * 32) * 32;
    const float* Bb = xN + ((size_t)(BATCH + b) * 1024) * 32;

    {
        int t = threadIdx.x;
        int w = t >> 3, gr = t & 7;
        f32x4 v = *(const f32x4*)&Ab[w * 32 + gr * 4];
        *(f32x4*)&sA[w * 32 + CSWZ(gr * 4, w)] = v;
    }
    for (int t = threadIdx.x; t < ROWS * 256; t += 256) {
        int row = t >> 8, q = t & 255;
        int w = q >> 3, gr = q & 7;
        int gh = h + half * 7 + row - 6;
        f32x4 v = {0.f, 0.f, 0.f, 0.f};
        if ((unsigned)gh < 32u) v = *(const f32x4*)&Bb[((size_t)gh * 32 + w) * 32 + gr * 4];
        *(f32x4*)&sB[row][w * 32 + CSWZ(gr * 4, w)] = v;
    }
    __syncthreads();

    const int w = threadIdx.x & 31;
    const int gq = threadIdx.x >> 5;     // 0..7
    if (gq < ROWS) {
        f32x4 a[8];
        #pragma unroll
        for (int gr = 0; gr < 8; ++gr) a[gr] = *(const f32x4*)&sA[w * 32 + CSWZ(gr * 4, w)];
        #pragma unroll
        for (int dx = 0; dx < 13; ++dx) {
            int wb = w + dx - 6;
            float s = 0.f;
            if ((unsigned)wb < 32u) {
                #pragma unroll
                for (int gr = 0; gr < 8; ++gr) {
                    f32x4 bv = *(const f32x4*)&sB[gq][wb * 32 + CSWZ(gr * 4, wb)];
                    s += a[gr].x * bv.x + a[gr].y * bv.y + a[gr].z * bv.z + a[gr].w * bv.w;
                }
            }
            sC[w][gq * 13 + dx] = f2bf(s);
        }
    }
    __syncthreads();

    const int ND = ROWS * 13;            // 91 or 78
    for (int t = threadIdx.x; t < 32 * ND; t += 256) {
        int ww = t / ND;
        int d  = t - ww * ND;
        cost[((size_t)(b * 1024) + h * 32 + ww) * 192 + half * 91 + d] = sC[ww][d];
    }
}

// ---------------------------------------------------------------------------
extern "C" void kernel_launch(void* const* d_in, const int* in_sizes, int n_in,
                              void* d_out, int out_size, void* d_ws, size_t ws_size,
                              hipStream_t stream)
{
    const float* frameA = (const float*)d_in[0];
    const float* frameB = (const float*)d_in[1];
    const float* w1  = (const float*)d_in[2];
    const float* b1  = (const float*)d_in[3];
    const float* g1  = (const float*)d_in[4];
    const float* be1 = (const float*)d_in[5];
    const float* w2  = (const float*)d_in[6];
    const float* b2  = (const float*)d_in[7];
    const float* g2  = (const float*)d_in[8];
    const float* be2 = (const float*)d_in[9];
    const float* w3  = (const float*)d_in[10];
    const float* b3  = (const float*)d_in[11];
    const float* g3  = (const float*)d_in[12];
    const float* be3 = (const float*)d_in[13];
    const float* wc1 = (const float*)d_in[14];
    const float* bc1 = (const float*)d_in[15];
    const float* wc2 = (const float*)d_in[16];
    const float* bc2 = (const float*)d_in[17];
    const float* wf1 = (const float*)d_in[18];
    const float* bf1 = (const float*)d_in[19];
    const float* wf2 = (const float*)d_in[20];
    const float* bf2 = (const float*)d_in[21];
    const float* wo  = (const float*)d_in[22];
    const float* bo  = (const float*)d_in[23];

    // workspace layout
    float* ws      = (float*)d_ws;
    float* c3N     = ws;                              // [64][1024][32] f32  2,097,152
    float* coarseN = c3N + 2097152;                   // [64][1024][32] f32  2,097,152
    float2* part1  = (float2*)(coarseN + 2097152);    // 4096  float2 (BN1, NS=128)
    float2* part2  = part1 + 4096;                    // 16384 float2 (BN2, NS=256)
    float2* part3  = part2 + 16384;                   // 16384 float2 (BN3, NS=256)
    unsigned short* fineN = (unsigned short*)(part3 + 16384);  // [64][64][64][16] pre-BN
    unsigned short* h2bf  = fineN + 4194304;   // [64][32][32][32]  pre-BN2
    unsigned short* costN = h2bf + 2097152;    // [B][32][32][192]
    unsigned short* d1    = costN + 6291456;   // [B][32][32][128]
    unsigned short* d2    = d1 + 4194304;      // [B][32][32][64]
    unsigned short* f1o   = d2 + 2097152;      // [B][64][64][64]
    unsigned short* wT1   = f1o + 8388608;     // 221,184 (swizzled images)
    unsigned short* wT2   = wT1 + 221184;      // 73,728
    unsigned short* wTf1  = wT2 + 73728;       // 55,296
    unsigned short* wTf2  = wTf1 + 55296;      // 18,432
    unsigned short* wE2   = wTf2 + 18432;      // 13,312
    unsigned short* wE3   = wE2 + 13312;       // 9,216
    unsigned short* zbuf  = wE3 + 9216;        // 16B zero granule

    const int T = 256;

    // 1. conv1 (512 blocks) + weight prep (1528 blocks) + zerobuf
    conv1_prep<<<2040, T, 0, stream>>>(frameA, frameB, w1, b1, fineN, part1,
                                       wc1, wc2, wf1, wf2, w2, w3,
                                       wT1, wT2, wTf1, wTf2, wE2, wE3, zbuf);

    // 2. conv2s: BN1 applied at staging; emits pre-BN2 + part2
    conv2s_mfma<<<dim3(8, 1, 64), T, 0, stream>>>(fineN, wE2, b2, h2bf,
                                                  part1, g1, be1, part2);

    // 3. conv3: BN2 applied at staging; f32 out + part3
    conv3x3_mfma<32, 32, 32, 8, 0, 3, 2><<<dim3(8, 1, 64), T, 0, stream>>>(
        h2bf, nullptr, wE3, b3, (unsigned short*)c3N, nullptr, nullptr, nullptr,
        part2, g2, be2, part3, zbuf);

    // 4. BN3 finalize + lrelu + L2-norm -> coarseN
    bn3_l2n_nhwc<<<256, T, 0, stream>>>(c3N, part3, g3, be3, coarseN);

    // 5. correlation (half-split, 2048 blocks)
    corr_split<<<dim3(32, BATCH, 2), T, 0, stream>>>(coarseN, costN);

    // 6-9. decoder
    conv3x3_mfma<192, 128, 32, 8, 0, 0, 0><<<dim3(8, 2, BATCH), T, 0, stream>>>(
        costN, nullptr, wT1, bc1, d1, nullptr, nullptr, nullptr,
        nullptr, nullptr, nullptr, nullptr, zbuf);
    conv3x3_mfma<128, 64, 32, 4, 0, 0, 0><<<dim3(16, 1, BATCH), T, 0, stream>>>(
        d1, nullptr, wT2, bc2, d2, nullptr, nullptr, nullptr,
        nullptr, nullptr, nullptr, nullptr, zbuf);
    conv3x3_mfma<96, 64, 64, 8, 1, 0, 1><<<dim3(32, 1, BATCH), T, 0, stream>>>(
        d2, fineN, wTf1, bf1, f1o, nullptr, nullptr, nullptr,
        part1, g1, be1, nullptr, zbuf);
    conv3x3_mfma<64, 32, 64, 16, 0, 2, 0><<<dim3(16, 1, BATCH), T, 0, stream>>>(
        f1o, nullptr, wTf2, bf2, nullptr, (float*)d_out, wo, bo,
        nullptr, nullptr, nullptr, nullptr, zbuf);
}